// Round 7
// baseline (254.113 us; speedup 1.0000x reference)
//
#include <hip/hip_runtime.h>
#include <stdint.h>
#include <stddef.h>

#define SEQ 2048
#define NH 16
#define DH 64
#define DM 1024
#define NROWS 8192  // B*T

typedef __attribute__((ext_vector_type(4))) float f32x4;
typedef __attribute__((ext_vector_type(16))) float f32x16;
typedef __attribute__((ext_vector_type(8))) short s16x8;
typedef __attribute__((ext_vector_type(4))) unsigned u32x4;

__device__ __forceinline__ unsigned short f2bf(float f) {
  unsigned int u = __builtin_bit_cast(unsigned int, f);
  u += 0x7fffu + ((u >> 16) & 1u);
  return (unsigned short)(u >> 16);
}

__device__ __forceinline__ float exp2fast(float x) {
#if __has_builtin(__builtin_amdgcn_exp2f)
  return __builtin_amdgcn_exp2f(x);
#else
  return exp2f(x);
#endif
}

__device__ __forceinline__ float rcpfast(float x) {
#if __has_builtin(__builtin_amdgcn_rcpf)
  return __builtin_amdgcn_rcpf(x);
#else
  return 1.0f / x;
#endif
}

// pack two f32 -> (bf16(lo) | bf16(hi)<<16), truncating (P in (0,1], rel err < 2^-8)
__device__ __forceinline__ unsigned pk2(float lo, float hi) {
  return __builtin_amdgcn_perm(__builtin_bit_cast(unsigned, hi),
                               __builtin_bit_cast(unsigned, lo), 0x07060302u);
}

// R2/R3 lesson: __builtin_amdgcn_permlane32_swap(u, u, ...) with the SAME value
// for both operands lets regalloc alias vdst==vsrc -> instruction degenerates to
// an in-place half swap; fmax(r0,r1) returns ONLY the partner half's value.
// Cross-half exchanges stay on the harness-proven __shfl_xor path.

__device__ __forceinline__ void async16(const void* g, void* l) {
  __builtin_amdgcn_global_load_lds(
      (const __attribute__((address_space(1))) unsigned int*)g,
      (__attribute__((address_space(3))) unsigned int*)l, 16, 0, 0);
}

// ---------------- fused fp32 -> bf16 cast: x + 4 weights, one launch ----------------
__global__ __launch_bounds__(256) void cast_all(const float* __restrict__ x,
                                                const float* __restrict__ w0,
                                                const float* __restrict__ w1,
                                                const float* __restrict__ w2,
                                                const float* __restrict__ w3,
                                                short* __restrict__ Xb,
                                                short* __restrict__ Wb) {
  int g = blockIdx.x * 256 + threadIdx.x;  // chunk of 8 floats
  const float* src;
  short* dst;
  int off;
  if (g < NROWS * DM / 8) {
    src = x; dst = Xb; off = g;
  } else {
    int r = g - NROWS * DM / 8;
    int w = r >> 17;             // 0..3  (DM*DM/8 = 131072 chunks per weight)
    off = r & 131071;
    src = (w == 0) ? w0 : (w == 1) ? w1 : (w == 2) ? w2 : w3;
    dst = Wb + ((size_t)w << 20);
  }
  const float4* s4 = (const float4*)src;
  float4 a = s4[2 * off], b = s4[2 * off + 1];
  s16x8 o;
  o[0] = (short)f2bf(a.x); o[1] = (short)f2bf(a.y);
  o[2] = (short)f2bf(a.z); o[3] = (short)f2bf(a.w);
  o[4] = (short)f2bf(b.x); o[5] = (short)f2bf(b.y);
  o[6] = (short)f2bf(b.z); o[7] = (short)f2bf(b.w);
  *(s16x8*)(dst + (size_t)8 * off) = o;
}

// ---------------- FUSED QKV projection GEMM (R6 structure, kept) ----------------
// BM=256, BK=32, double-buffered 80KB dynamic LDS, grid (8,32) = 1 block/CU,
// bn-column pinned per XCD. R6 post-mortem: ~neutral vs R5 kernel itself, but
// the per-XCD write pattern correlated with attn -11us (L2 placement) -> keep.
__global__ __launch_bounds__(512, 2) void gemm_qkv(const short* __restrict__ X,
                                                   const short* __restrict__ Wq,
                                                   const short* __restrict__ Wk,
                                                   const short* __restrict__ Wv,
                                                   short* __restrict__ Qo,
                                                   short* __restrict__ Ko,
                                                   short* __restrict__ Vo) {
  extern __shared__ __align__(16) short smem[];  // 2 x (X 8192 | W0 4096 | W1 4096 | W2 4096)
  const int tid = threadIdx.x;
  const int lane = tid & 63, wave = tid >> 6;
  const int l15 = lane & 15, quad = lane >> 4;
  const int bn = blockIdx.x * 128;
  const int bm = blockIdx.y * 256;
  const int wm = (wave >> 1) * 64, wn = (wave & 1) * 64;

  const short* Ab = X + (size_t)bm * DM;
  const short* W0 = Wq + (size_t)bn * DM;
  const short* W1 = Wk + (size_t)bn * DM;
  const short* W2 = Wv + (size_t)bn * DM;

  f32x4 acc[3][4][4];
#pragma unroll
  for (int g = 0; g < 3; g++)
#pragma unroll
    for (int i = 0; i < 4; i++)
#pragma unroll
      for (int j = 0; j < 4; j++) acc[g][i][j] = (f32x4)0.f;

  auto stage = [&](int k, int buf) {
    short* base = smem + buf * 20480;
    const int k0 = k * 32;
#pragma unroll
    for (int i = 0; i < 2; i++) {
      int f = i * 512 + tid;
      int row = f >> 2;
      int c = ((f & 3) ^ (row & 3) ^ ((row >> 2) & 1)) * 8;
      async16(Ab + (size_t)row * DM + k0 + c, base + (size_t)f * 8);
    }
    {
      int f = tid;
      int row = f >> 2;
      int c = ((f & 3) ^ (row & 3) ^ ((row >> 2) & 1)) * 8;
      size_t go = (size_t)row * DM + k0 + c;
      async16(W0 + go, base + 8192 + (size_t)f * 8);
      async16(W1 + go, base + 12288 + (size_t)f * 8);
      async16(W2 + go, base + 16384 + (size_t)f * 8);
    }
  };

  stage(0, 0);
  __syncthreads();

  const int sl = (l15 & 3) ^ ((l15 >> 2) & 1);
  for (int k = 0; k < 32; k++) {
    const int buf = k & 1;
    if (k < 31) stage(k + 1, buf ^ 1);  // prefetch rides under compute(k)
    const short* base = smem + buf * 20480;

    s16x8 af[4];
#pragma unroll
    for (int t = 0; t < 4; t++)
      af[t] = *(const s16x8*)(base + (size_t)(wm + t * 16 + l15) * 32 + (size_t)((quad ^ sl) * 8));
#pragma unroll
    for (int g = 0; g < 3; g++) {
      const short* wb = base + 8192 + g * 4096;
      s16x8 bfr[4];
#pragma unroll
      for (int t = 0; t < 4; t++)
        bfr[t] = *(const s16x8*)(wb + (size_t)(wn + t * 16 + l15) * 32 + (size_t)((quad ^ sl) * 8));
#pragma unroll
      for (int mt = 0; mt < 4; mt++)
#pragma unroll
        for (int nt = 0; nt < 4; nt++) {
          if (g == 2)  // V: swap operands so tokens land in lanes (coalesced V^T store)
            acc[2][mt][nt] = __builtin_amdgcn_mfma_f32_16x16x32_bf16(bfr[nt], af[mt], acc[2][mt][nt], 0, 0, 0);
          else
            acc[g][mt][nt] = __builtin_amdgcn_mfma_f32_16x16x32_bf16(af[mt], bfr[nt], acc[g][mt][nt], 0, 0, 0);
        }
    }
    __syncthreads();
  }

  // Q, K: [B,NH,SEQ,DH] scatter
#pragma unroll
  for (int g = 0; g < 2; g++) {
    short* Dst = g ? Ko : Qo;
#pragma unroll
    for (int mt = 0; mt < 4; mt++)
#pragma unroll
      for (int r = 0; r < 4; r++)
#pragma unroll
        for (int nt = 0; nt < 4; nt++) {
          int m = bm + wm + mt * 16 + quad * 4 + r;
          int n = bn + wn + nt * 16 + l15;
          int b = m >> 11, t = m & (SEQ - 1);
          int hh = n >> 6, d = n & 63;
          Dst[((((size_t)b * NH + hh) * SEQ + t) << 6) + d] = (short)f2bf(acc[g][mt][nt][r]);
        }
  }
  // V: [B,NH,DH,SEQ] (transposed D: col = token, row = d)
#pragma unroll
  for (int mt = 0; mt < 4; mt++)
#pragma unroll
    for (int r = 0; r < 4; r++)
#pragma unroll
      for (int nt = 0; nt < 4; nt++) {
        int n = bn + wn + nt * 16 + quad * 4 + r;  // d-dim
        int m = bm + wm + mt * 16 + l15;           // token
        int b = m >> 11, t = m & (SEQ - 1);
        int hh = n >> 6, d = n & 63;
        Vo[(((size_t)b * NH + hh) * DH + d) * SEQ + t] = (short)f2bf(acc[2][mt][nt][r]);
      }
}

// ---------------- output projection GEMM, 256x128 supertile, fp32 out ----------------
__global__ __launch_bounds__(256, 2) void gemm_o(const short* __restrict__ A,
                                                 const short* __restrict__ B,
                                                 float* __restrict__ C) {
  __shared__ __align__(16) short As[256 * 64];
  __shared__ __align__(16) short Bs[128 * 64];
  const int tid = threadIdx.x;
  const int lane = tid & 63, wave = tid >> 6;
  const int l15 = lane & 15, quad = lane >> 4;
  const int bm = blockIdx.y * 256, bn = blockIdx.x * 128;
  const int wm = (wave >> 1) * 128, wn = (wave & 1) * 64;

  const short* Ab = A + (size_t)bm * DM;
  const short* Bb = B + (size_t)bn * DM;

  f32x4 acc[8][4];
#pragma unroll
  for (int i = 0; i < 8; i++)
#pragma unroll
    for (int j = 0; j < 4; j++) acc[i][j] = (f32x4)0.f;

  for (int k0 = 0; k0 < DM; k0 += 64) {
#pragma unroll
    for (int i = 0; i < 8; i++) {
      int f = i * 256 + tid;
      int row = f >> 3, c = ((f & 7) ^ (row & 7)) * 8;
      async16(Ab + (size_t)row * DM + k0 + c, As + (size_t)f * 8);
    }
#pragma unroll
    for (int i = 0; i < 4; i++) {
      int f = i * 256 + tid;
      int row = f >> 3, c = ((f & 7) ^ (row & 7)) * 8;
      async16(Bb + (size_t)row * DM + k0 + c, Bs + (size_t)f * 8);
    }
    __syncthreads();
#pragma unroll
    for (int ks = 0; ks < 2; ks++) {
      s16x8 bfr[4];
#pragma unroll
      for (int t = 0; t < 4; t++)
        bfr[t] = *(const s16x8*)(Bs + (wn + t * 16 + l15) * 64 + (((ks * 4 + quad) ^ (l15 & 7)) * 8));
#pragma unroll
      for (int mt = 0; mt < 8; mt++) {
        s16x8 af = *(const s16x8*)(As + (wm + mt * 16 + l15) * 64 + (((ks * 4 + quad) ^ (l15 & 7)) * 8));
#pragma unroll
        for (int nt = 0; nt < 4; nt++)
          acc[mt][nt] = __builtin_amdgcn_mfma_f32_16x16x32_bf16(af, bfr[nt], acc[mt][nt], 0, 0, 0);
      }
    }
    __syncthreads();
  }

#pragma unroll
  for (int mt = 0; mt < 8; mt++)
#pragma unroll
    for (int r = 0; r < 4; r++) {
      int m = bm + wm + mt * 16 + quad * 4 + r;
#pragma unroll
      for (int nt = 0; nt < 4; nt++)
        C[(size_t)m * DM + bn + wn + nt * 16 + l15] = acc[mt][nt][r];
    }
}

// ---------------- causal flash attention (R7: QBLK=256, 8 waves) ----------------
// R6 counters: occupancy 18% vs 25% hard cap (2 blk/CU @ 64KB), per-iteration
// wall ~10k cyc vs ~1k cyc of issue work -> latency-exposed serial chain, too
// few waves/SIMD to fill bubbles. QBLK 128->256 at 512 threads: same per-wave
// math (32 q-rows/wave, identical LDS layouts/softmax/pack/PV), but
//  - 2 blocks/CU now = 16 waves/CU = 4/SIMD (50% occ ceiling, 2x R6)
//  - k-tile visits per chip nearly halve (each staged K/V serves 256 q-rows)
//  - grid 512 = exactly 2/CU, LPT-paired: first half qb=7..4, second qb=0..3
//    -> each CU ~(16+2)..(10+8)=18 iteration-units, near-perfect balance.
// Causal mask generalized: limit = q0 - kt*128 + wave*32 + l31 - 4h, applied
// on the last two k-tiles only (below-diagonal waves get limit>=124 -> no-op;
// above-diagonal waves go full -inf -> exp=0, alpha=1: harmless).
// VGPR 108 < 128 cap @ (512,2). Epilogue scratch per-wave (8x1056 f32 = 34KB).
__global__ __launch_bounds__(512, 2) void attn_kernel(const short* __restrict__ Q,
                                                      const short* __restrict__ K,
                                                      const short* __restrict__ V,
                                                      short* __restrict__ O) {
  __shared__ __align__(16) short Smem[2 * 16384];  // buf b: K at b*16384, V at +8192

  const int tid = threadIdx.x;
  const int lane = tid & 63, wave = tid >> 6;
  const int l31 = lane & 31, h = lane >> 5;

  const int r = blockIdx.x & 63;
  const int half = blockIdx.x >> 8;                 // 0: first 256 blocks, 1: rest
  const int g64 = (blockIdx.x >> 6) & 3;
  const int qb = half ? g64 : 7 - g64;              // LPT pairs (7,0)(6,1)(5,2)(4,3)
  const int bh = (r & 7) * 8 + (r >> 3);            // XCD (blockIdx%8) -> bh octet
  const int q0 = qb * 256;
  const int nk = 2 * qb + 2;                        // k-tiles of 128

  const short* Qb = Q + (size_t)bh * SEQ * DH;
  const short* Kb = K + (size_t)bh * SEQ * DH;
  const short* Vb = V + (size_t)bh * DH * SEQ;

  auto stageK = [&](int ktile, int buf) {
    short* base = Smem + buf * 16384;
    const short* ksrc = Kb + (size_t)ktile * 128 * DH;
#pragma unroll
    for (int i = 0; i < 2; i++) {
      int f = i * 512 + tid;
      int kk = f >> 3, c8 = (f & 7) ^ (kk & 7);
      async16(ksrc + (size_t)kk * DH + c8 * 8, base + (size_t)f * 8);
    }
  };
  auto stageV = [&](int ktile, int buf) {
    short* base = Smem + buf * 16384 + 8192;
    const short* vsrc = Vb + (size_t)ktile * 128;
#pragma unroll
    for (int i = 0; i < 2; i++) {
      int f = i * 512 + tid;
      int d = f >> 4, c16 = (f & 15) ^ (d & 15);
      async16(vsrc + (size_t)d * SEQ + c16 * 8, base + (size_t)f * 8);
    }
  };

  s16x8 qf[4];
#pragma unroll
  for (int ks = 0; ks < 4; ks++)
    qf[ks] = *(const s16x8*)(Qb + (size_t)(q0 + wave * 32 + l31) * DH + ks * 16 + h * 8);

  f32x16 oacc[2];
  oacc[0] = (f32x16)0.f;
  oacc[1] = (f32x16)0.f;
  float m_own = -3.0e38f, l_own = 0.f, aprev = 0.f;
  s16x8 pf[8];  // P fragments of the PREVIOUS tile (consumed next iter)
  const float C = 0.18033688011112042f;  // (1/sqrt(64)) * log2(e)

  stageK(0, 0);

  for (int kt = 0; kt < nk; kt++) {
    const int cur = kt & 1;
    __syncthreads();  // K[kt] + V[kt-1] resident; all prior LDS reads done
    if (kt < nk - 1) stageK(kt + 1, cur ^ 1);
    stageV(kt, cur);  // consumed by PV in iter kt+1 (or post-loop peel)
    const short* Ks = Smem + cur * 16384;

    // ---- QK^T(kt) ----
    f32x16 sacc[4];
#pragma unroll
    for (int T = 0; T < 4; T++) sacc[T] = (f32x16)0.f;
#pragma unroll
    for (int ks = 0; ks < 4; ks++) {
#pragma unroll
      for (int T = 0; T < 4; T++) {
        s16x8 kf = *(const s16x8*)(Ks + (T * 32 + l31) * 64 + (((2 * ks + h) ^ (l31 & 7)) * 8));
        sacc[T] = __builtin_amdgcn_mfma_f32_32x32x16_bf16(kf, qf[ks], sacc[T], 0, 0, 0);
      }
    }

    // ---- deferred PV(kt-1): independent of this tile's softmax, overlaps it ----
    if (kt > 0) {
      const short* Vp = Smem + (cur ^ 1) * 16384 + 8192;
#pragma unroll
      for (int r2 = 0; r2 < 16; r2++) {
        oacc[0][r2] *= aprev;
        oacc[1][r2] *= aprev;
      }
#pragma unroll
      for (int kc = 0; kc < 8; kc++) {
#pragma unroll
        for (int td = 0; td < 2; td++) {
          s16x8 vf = *(const s16x8*)(Vp + (td * 32 + l31) * 128 + (((2 * kc + h) ^ (l31 & 15)) * 8));
          oacc[td] = __builtin_amdgcn_mfma_f32_32x32x16_bf16(vf, pf[kc], oacc[td], 0, 0, 0);
        }
      }
    }

    // ---- mask + online softmax(kt) ----
    if (kt >= nk - 2) {  // diagonal band (last two k-tiles)
      int limit = q0 - kt * 128 + wave * 32 + l31 - 4 * h;
#pragma unroll
      for (int T = 0; T < 4; T++)
#pragma unroll
        for (int r2 = 0; r2 < 16; r2++) {
          int kkc = T * 32 + (r2 & 3) + 8 * (r2 >> 2);
          if (kkc > limit) sacc[T][r2] = -3.0e38f;
        }
    }

    float tm[4];
#pragma unroll
    for (int T = 0; T < 4; T++) {
      float a = fmaxf(fmaxf(sacc[T][0], sacc[T][1]), fmaxf(sacc[T][2], sacc[T][3]));
      float b = fmaxf(fmaxf(sacc[T][4], sacc[T][5]), fmaxf(sacc[T][6], sacc[T][7]));
      float cc = fmaxf(fmaxf(sacc[T][8], sacc[T][9]), fmaxf(sacc[T][10], sacc[T][11]));
      float d = fmaxf(fmaxf(sacc[T][12], sacc[T][13]), fmaxf(sacc[T][14], sacc[T][15]));
      tm[T] = fmaxf(fmaxf(a, b), fmaxf(cc, d));
    }
    float mx = fmaxf(fmaxf(tm[0], tm[1]), fmaxf(tm[2], tm[3]));
    mx = fmaxf(mx, __shfl_xor(mx, 32, 64));
    float mnew = fmaxf(m_own, mx);
    float mb = mnew * C;
    float alpha = exp2fast(m_own * C - mb);
    m_own = mnew;

    float ts[4];
#pragma unroll
    for (int T = 0; T < 4; T++) {
#pragma unroll
      for (int r2 = 0; r2 < 16; r2++) sacc[T][r2] = exp2fast(fmaf(sacc[T][r2], C, -mb));
      float a = (sacc[T][0] + sacc[T][1]) + (sacc[T][2] + sacc[T][3]);
      float b = (sacc[T][4] + sacc[T][5]) + (sacc[T][6] + sacc[T][7]);
      float cc = (sacc[T][8] + sacc[T][9]) + (sacc[T][10] + sacc[T][11]);
      float d = (sacc[T][12] + sacc[T][13]) + (sacc[T][14] + sacc[T][15]);
      ts[T] = (a + b) + (cc + d);
    }
    float rsum = (ts[0] + ts[1]) + (ts[2] + ts[3]);
    rsum += __shfl_xor(rsum, 32, 64);
    l_own = l_own * alpha + rsum;

    // ---- pack P(kt) -> pf for next iteration's PV (proven shfl_xor path) ----
#pragma unroll
    for (int T = 0; T < 4; T++) {
      unsigned P0 = pk2(sacc[T][0], sacc[T][1]);
      unsigned P1 = pk2(sacc[T][2], sacc[T][3]);
      unsigned P2 = pk2(sacc[T][4], sacc[T][5]);
      unsigned P3 = pk2(sacc[T][6], sacc[T][7]);
      unsigned P4 = pk2(sacc[T][8], sacc[T][9]);
      unsigned P5 = pk2(sacc[T][10], sacc[T][11]);
      unsigned P6 = pk2(sacc[T][12], sacc[T][13]);
      unsigned P7 = pk2(sacc[T][14], sacc[T][15]);
      unsigned R0 = (unsigned)__shfl_xor((int)(h ? P0 : P2), 32, 64);
      unsigned R1 = (unsigned)__shfl_xor((int)(h ? P1 : P3), 32, 64);
      unsigned R2 = (unsigned)__shfl_xor((int)(h ? P4 : P6), 32, 64);
      unsigned R3 = (unsigned)__shfl_xor((int)(h ? P5 : P7), 32, 64);
      u32x4 lo, hi;
      lo[0] = h ? R0 : P0; lo[1] = h ? R1 : P1; lo[2] = h ? P2 : R0; lo[3] = h ? P3 : R1;
      hi[0] = h ? R2 : P4; hi[1] = h ? R3 : P5; hi[2] = h ? P6 : R2; hi[3] = h ? P7 : R3;
      pf[2 * T] = __builtin_bit_cast(s16x8, lo);
      pf[2 * T + 1] = __builtin_bit_cast(s16x8, hi);
    }

    aprev = alpha;
  }

  // ---- peeled final PV(nk-1) ----
  __syncthreads();  // drains V[nk-1] stage; all waves past their last LDS reads
  {
    const short* Vp = Smem + ((nk - 1) & 1) * 16384 + 8192;
#pragma unroll
    for (int r2 = 0; r2 < 16; r2++) {
      oacc[0][r2] *= aprev;
      oacc[1][r2] *= aprev;
    }
#pragma unroll
    for (int kc = 0; kc < 8; kc++) {
#pragma unroll
      for (int td = 0; td < 2; td++) {
        s16x8 vf = *(const s16x8*)(Vp + (td * 32 + l31) * 128 + (((2 * kc + h) ^ (l31 & 15)) * 8));
        oacc[td] = __builtin_amdgcn_mfma_f32_32x32x16_bf16(vf, pf[kc], oacc[td], 0, 0, 0);
      }
    }
  }
  __syncthreads();  // epilogue scratch below overlaps the K/V LDS regions

  const int b = bh >> 4, head = bh & 15;
  float inv = rcpfast(l_own);
  const int g = lane >> 3, d4 = (lane & 7) * 4;
#pragma unroll
  for (int td = 0; td < 2; td++) {
    // per-wave scratch, reused across td phases (same-wave LDS RAW/WAR is
    // ordered by compiler-inserted lgkmcnt waits)
    float* tb = (float*)Smem + (size_t)wave * 1056;  // 32 d-rows x 33 (pad)
#pragma unroll
    for (int r2 = 0; r2 < 16; r2++) {
      int d_loc = (r2 & 3) + 8 * (r2 >> 2) + 4 * h;
      tb[d_loc * 33 + l31] = oacc[td][r2] * inv;
    }
#pragma unroll
    for (int j = 0; j < 4; j++) {
      int qq = j * 8 + g;
      float x0 = tb[(d4 + 0) * 33 + qq];
      float x1 = tb[(d4 + 1) * 33 + qq];
      float x2 = tb[(d4 + 2) * 33 + qq];
      float x3 = tb[(d4 + 3) * 33 + qq];
      uint2 pkd;
      pkd.x = (unsigned)f2bf(x0) | ((unsigned)f2bf(x1) << 16);
      pkd.y = (unsigned)f2bf(x2) | ((unsigned)f2bf(x3) << 16);
      int q = q0 + wave * 32 + qq;
      *(uint2*)(O + ((size_t)(b * SEQ + q)) * DM + head * DH + td * 32 + d4) = pkd;
    }
  }
}

// ---------------- host launch ----------------
extern "C" void kernel_launch(void* const* d_in, const int* in_sizes, int n_in,
                              void* d_out, int out_size, void* d_ws, size_t ws_size,
                              hipStream_t stream) {
  const float* x  = (const float*)d_in[0];
  const float* wq = (const float*)d_in[1];
  const float* wk = (const float*)d_in[2];
  const float* wv = (const float*)d_in[3];
  const float* wo = (const float*)d_in[4];

  short* ws = (short*)d_ws;
  short* Xb  = ws;
  short* Wqb = Xb + (size_t)NROWS * DM;     // 4 weights contiguous from here
  short* Wkb = Wqb + (size_t)DM * DM;
  short* Wvb = Wkb + (size_t)DM * DM;
  short* Wob = Wvb + (size_t)DM * DM;
  short* Qb  = Wob + (size_t)DM * DM;       // [B,NH,SEQ,DH]
  short* Kb  = Qb + (size_t)NROWS * DM;
  short* Vtb = Kb + (size_t)NROWS * DM;     // [B,NH,DH,SEQ]
  short* Ob  = Xb;                          // alias: X dead after QKV GEMMs

  // opt-in for 80KB dynamic LDS (host-side attribute, not a stream op ->
  // graph-capture safe; idempotent)
  static bool attr_done = false;
  if (!attr_done) {
    (void)hipFuncSetAttribute((const void*)gemm_qkv,
                              hipFuncAttributeMaxDynamicSharedMemorySize, 81920);
    attr_done = true;
  }

  int total_chunks = NROWS * DM / 8 + 4 * (DM * DM / 8);
  cast_all<<<total_chunks / 256, 256, 0, stream>>>(x, wq, wk, wv, wo, Xb, Wqb);

  gemm_qkv<<<dim3(8, 32), 512, 81920, stream>>>(Xb, Wqb, Wkb, Wvb, Qb, Kb, Vtb);

  attn_kernel<<<512, 512, 0, stream>>>(Qb, Kb, Vtb, Ob);

  gemm_o<<<dim3(8, 32), 256, 0, stream>>>(Ob, Wob, (float*)d_out);
}

// Round 8
// 247.633 us; speedup vs baseline: 1.0262x; 1.0262x over previous
//
#include <hip/hip_runtime.h>
#include <stdint.h>
#include <stddef.h>

#define SEQ 2048
#define NH 16
#define DH 64
#define DM 1024
#define NROWS 8192  // B*T

typedef __attribute__((ext_vector_type(4))) float f32x4;
typedef __attribute__((ext_vector_type(16))) float f32x16;
typedef __attribute__((ext_vector_type(8))) short s16x8;
typedef __attribute__((ext_vector_type(4))) unsigned u32x4;

__device__ __forceinline__ unsigned short f2bf(float f) {
  unsigned int u = __builtin_bit_cast(unsigned int, f);
  u += 0x7fffu + ((u >> 16) & 1u);
  return (unsigned short)(u >> 16);
}

__device__ __forceinline__ float exp2fast(float x) {
#if __has_builtin(__builtin_amdgcn_exp2f)
  return __builtin_amdgcn_exp2f(x);
#else
  return exp2f(x);
#endif
}

__device__ __forceinline__ float rcpfast(float x) {
#if __has_builtin(__builtin_amdgcn_rcpf)
  return __builtin_amdgcn_rcpf(x);
#else
  return 1.0f / x;
#endif
}

// pack two f32 -> (bf16(lo) | bf16(hi)<<16), truncating (P in (0,1], rel err < 2^-8)
__device__ __forceinline__ unsigned pk2(float lo, float hi) {
  return __builtin_amdgcn_perm(__builtin_bit_cast(unsigned, hi),
                               __builtin_bit_cast(unsigned, lo), 0x07060302u);
}

// R2/R3 lesson: __builtin_amdgcn_permlane32_swap(u, u, ...) with the SAME value
// for both operands lets regalloc alias vdst==vsrc -> instruction degenerates to
// an in-place half swap; fmax(r0,r1) returns ONLY the partner half's value.
// Cross-half exchanges stay on the harness-proven __shfl_xor path.
// R7 lesson: occupancy CEILING is not achieved occupancy. 512 blocks into 512
// residency slots = no backfill queue -> short/long pairing leaves CUs half
// empty (attn 72.7->81.4us). Keep 1024 small blocks + LPT; don't merge blocks.

__device__ __forceinline__ void async16(const void* g, void* l) {
  __builtin_amdgcn_global_load_lds(
      (const __attribute__((address_space(1))) unsigned int*)g,
      (__attribute__((address_space(3))) unsigned int*)l, 16, 0, 0);
}

// ---------------- fused fp32 -> bf16 cast: x + 4 weights, one launch ----------------
__global__ __launch_bounds__(256) void cast_all(const float* __restrict__ x,
                                                const float* __restrict__ w0,
                                                const float* __restrict__ w1,
                                                const float* __restrict__ w2,
                                                const float* __restrict__ w3,
                                                short* __restrict__ Xb,
                                                short* __restrict__ Wb) {
  int g = blockIdx.x * 256 + threadIdx.x;  // chunk of 8 floats
  const float* src;
  short* dst;
  int off;
  if (g < NROWS * DM / 8) {
    src = x; dst = Xb; off = g;
  } else {
    int r = g - NROWS * DM / 8;
    int w = r >> 17;             // 0..3  (DM*DM/8 = 131072 chunks per weight)
    off = r & 131071;
    src = (w == 0) ? w0 : (w == 1) ? w1 : (w == 2) ? w2 : w3;
    dst = Wb + ((size_t)w << 20);
  }
  const float4* s4 = (const float4*)src;
  float4 a = s4[2 * off], b = s4[2 * off + 1];
  s16x8 o;
  o[0] = (short)f2bf(a.x); o[1] = (short)f2bf(a.y);
  o[2] = (short)f2bf(a.z); o[3] = (short)f2bf(a.w);
  o[4] = (short)f2bf(b.x); o[5] = (short)f2bf(b.y);
  o[6] = (short)f2bf(b.z); o[7] = (short)f2bf(b.w);
  *(s16x8*)(dst + (size_t)8 * off) = o;
}

// ---------------- FUSED QKV projection GEMM (R6 structure, kept) ----------------
// BM=256, BK=32, double-buffered 80KB dynamic LDS, grid (8,32) = 1 block/CU,
// bn-column pinned per XCD. R6 post-mortem: ~neutral vs R5 kernel itself, but
// the per-XCD write pattern correlated with attn -11us (L2 placement) -> keep.
__global__ __launch_bounds__(512, 2) void gemm_qkv(const short* __restrict__ X,
                                                   const short* __restrict__ Wq,
                                                   const short* __restrict__ Wk,
                                                   const short* __restrict__ Wv,
                                                   short* __restrict__ Qo,
                                                   short* __restrict__ Ko,
                                                   short* __restrict__ Vo) {
  extern __shared__ __align__(16) short smem[];  // 2 x (X 8192 | W0 4096 | W1 4096 | W2 4096)
  const int tid = threadIdx.x;
  const int lane = tid & 63, wave = tid >> 6;
  const int l15 = lane & 15, quad = lane >> 4;
  const int bn = blockIdx.x * 128;
  const int bm = blockIdx.y * 256;
  const int wm = (wave >> 1) * 64, wn = (wave & 1) * 64;

  const short* Ab = X + (size_t)bm * DM;
  const short* W0 = Wq + (size_t)bn * DM;
  const short* W1 = Wk + (size_t)bn * DM;
  const short* W2 = Wv + (size_t)bn * DM;

  f32x4 acc[3][4][4];
#pragma unroll
  for (int g = 0; g < 3; g++)
#pragma unroll
    for (int i = 0; i < 4; i++)
#pragma unroll
      for (int j = 0; j < 4; j++) acc[g][i][j] = (f32x4)0.f;

  auto stage = [&](int k, int buf) {
    short* base = smem + buf * 20480;
    const int k0 = k * 32;
#pragma unroll
    for (int i = 0; i < 2; i++) {
      int f = i * 512 + tid;
      int row = f >> 2;
      int c = ((f & 3) ^ (row & 3) ^ ((row >> 2) & 1)) * 8;
      async16(Ab + (size_t)row * DM + k0 + c, base + (size_t)f * 8);
    }
    {
      int f = tid;
      int row = f >> 2;
      int c = ((f & 3) ^ (row & 3) ^ ((row >> 2) & 1)) * 8;
      size_t go = (size_t)row * DM + k0 + c;
      async16(W0 + go, base + 8192 + (size_t)f * 8);
      async16(W1 + go, base + 12288 + (size_t)f * 8);
      async16(W2 + go, base + 16384 + (size_t)f * 8);
    }
  };

  stage(0, 0);
  __syncthreads();

  const int sl = (l15 & 3) ^ ((l15 >> 2) & 1);
  for (int k = 0; k < 32; k++) {
    const int buf = k & 1;
    if (k < 31) stage(k + 1, buf ^ 1);  // prefetch rides under compute(k)
    const short* base = smem + buf * 20480;

    s16x8 af[4];
#pragma unroll
    for (int t = 0; t < 4; t++)
      af[t] = *(const s16x8*)(base + (size_t)(wm + t * 16 + l15) * 32 + (size_t)((quad ^ sl) * 8));
#pragma unroll
    for (int g = 0; g < 3; g++) {
      const short* wb = base + 8192 + g * 4096;
      s16x8 bfr[4];
#pragma unroll
      for (int t = 0; t < 4; t++)
        bfr[t] = *(const s16x8*)(wb + (size_t)(wn + t * 16 + l15) * 32 + (size_t)((quad ^ sl) * 8));
#pragma unroll
      for (int mt = 0; mt < 4; mt++)
#pragma unroll
        for (int nt = 0; nt < 4; nt++) {
          if (g == 2)  // V: swap operands so tokens land in lanes (coalesced V^T store)
            acc[2][mt][nt] = __builtin_amdgcn_mfma_f32_16x16x32_bf16(bfr[nt], af[mt], acc[2][mt][nt], 0, 0, 0);
          else
            acc[g][mt][nt] = __builtin_amdgcn_mfma_f32_16x16x32_bf16(af[mt], bfr[nt], acc[g][mt][nt], 0, 0, 0);
        }
    }
    __syncthreads();
  }

  // Q, K: [B,NH,SEQ,DH] scatter
#pragma unroll
  for (int g = 0; g < 2; g++) {
    short* Dst = g ? Ko : Qo;
#pragma unroll
    for (int mt = 0; mt < 4; mt++)
#pragma unroll
      for (int r = 0; r < 4; r++)
#pragma unroll
        for (int nt = 0; nt < 4; nt++) {
          int m = bm + wm + mt * 16 + quad * 4 + r;
          int n = bn + wn + nt * 16 + l15;
          int b = m >> 11, t = m & (SEQ - 1);
          int hh = n >> 6, d = n & 63;
          Dst[((((size_t)b * NH + hh) * SEQ + t) << 6) + d] = (short)f2bf(acc[g][mt][nt][r]);
        }
  }
  // V: [B,NH,DH,SEQ] (transposed D: col = token, row = d)
#pragma unroll
  for (int mt = 0; mt < 4; mt++)
#pragma unroll
    for (int r = 0; r < 4; r++)
#pragma unroll
      for (int nt = 0; nt < 4; nt++) {
        int n = bn + wn + nt * 16 + quad * 4 + r;  // d-dim
        int m = bm + wm + mt * 16 + l15;           // token
        int b = m >> 11, t = m & (SEQ - 1);
        int hh = n >> 6, d = n & 63;
        Vo[(((size_t)b * NH + hh) * DH + d) * SEQ + t] = (short)f2bf(acc[2][mt][nt][r]);
      }
}

// ---------------- output projection GEMM, 256x128 supertile, fp32 out ----------------
__global__ __launch_bounds__(256, 2) void gemm_o(const short* __restrict__ A,
                                                 const short* __restrict__ B,
                                                 float* __restrict__ C) {
  __shared__ __align__(16) short As[256 * 64];
  __shared__ __align__(16) short Bs[128 * 64];
  const int tid = threadIdx.x;
  const int lane = tid & 63, wave = tid >> 6;
  const int l15 = lane & 15, quad = lane >> 4;
  const int bm = blockIdx.y * 256, bn = blockIdx.x * 128;
  const int wm = (wave >> 1) * 128, wn = (wave & 1) * 64;

  const short* Ab = A + (size_t)bm * DM;
  const short* Bb = B + (size_t)bn * DM;

  f32x4 acc[8][4];
#pragma unroll
  for (int i = 0; i < 8; i++)
#pragma unroll
    for (int j = 0; j < 4; j++) acc[i][j] = (f32x4)0.f;

  for (int k0 = 0; k0 < DM; k0 += 64) {
#pragma unroll
    for (int i = 0; i < 8; i++) {
      int f = i * 256 + tid;
      int row = f >> 3, c = ((f & 7) ^ (row & 7)) * 8;
      async16(Ab + (size_t)row * DM + k0 + c, As + (size_t)f * 8);
    }
#pragma unroll
    for (int i = 0; i < 4; i++) {
      int f = i * 256 + tid;
      int row = f >> 3, c = ((f & 7) ^ (row & 7)) * 8;
      async16(Bb + (size_t)row * DM + k0 + c, Bs + (size_t)f * 8);
    }
    __syncthreads();
#pragma unroll
    for (int ks = 0; ks < 2; ks++) {
      s16x8 bfr[4];
#pragma unroll
      for (int t = 0; t < 4; t++)
        bfr[t] = *(const s16x8*)(Bs + (wn + t * 16 + l15) * 64 + (((ks * 4 + quad) ^ (l15 & 7)) * 8));
#pragma unroll
      for (int mt = 0; mt < 8; mt++) {
        s16x8 af = *(const s16x8*)(As + (wm + mt * 16 + l15) * 64 + (((ks * 4 + quad) ^ (l15 & 7)) * 8));
#pragma unroll
        for (int nt = 0; nt < 4; nt++)
          acc[mt][nt] = __builtin_amdgcn_mfma_f32_16x16x32_bf16(af, bfr[nt], acc[mt][nt], 0, 0, 0);
      }
    }
    __syncthreads();
  }

#pragma unroll
  for (int mt = 0; mt < 8; mt++)
#pragma unroll
    for (int r = 0; r < 4; r++) {
      int m = bm + wm + mt * 16 + quad * 4 + r;
#pragma unroll
      for (int nt = 0; nt < 4; nt++)
        C[(size_t)m * DM + bn + wn + nt * 16 + l15] = acc[mt][nt][r];
    }
}

// ---------------- causal flash attention (R8 = R6 proven kernel + setprio) ----------------
// R6 structure (proven 72.7us): QBLK=128, 256 threads, 64KB LDS, one barrier
// per iter, deferred PV, LPT dispatch (qt = 15 - blockIdx>>6), XCD-pinned bh.
// R8 adds T5 s_setprio(1) around the MFMA clusters: two independent 4-wave
// blocks share each CU; setprio biases the scheduler toward the MFMA-entering
// wave when the co-resident block is in its softmax VALU phase (m191 regime:
// independent blocks, +4-7%). No math/sync change.
__global__ __launch_bounds__(256, 2) void attn_kernel(const short* __restrict__ Q,
                                                      const short* __restrict__ K,
                                                      const short* __restrict__ V,
                                                      short* __restrict__ O) {
  __shared__ __align__(16) short Smem[2 * 16384];  // buf b: K at b*16384, V at +8192

  const int tid = threadIdx.x;
  const int lane = tid & 63, wave = tid >> 6;
  const int l31 = lane & 31, h = lane >> 5;

  const int r = blockIdx.x & 63;
  const int qt = 15 - (blockIdx.x >> 6);     // LPT: longest blocks dispatch first
  const int bh = (r & 7) * 8 + (r >> 3);     // XCD (blockIdx%8) -> bh octet
  const int q0 = qt * 128;

  const short* Qb = Q + (size_t)bh * SEQ * DH;
  const short* Kb = K + (size_t)bh * SEQ * DH;
  const short* Vb = V + (size_t)bh * DH * SEQ;

  auto stageK = [&](int ktile, int buf) {
    short* base = Smem + buf * 16384;
    const short* ksrc = Kb + (size_t)ktile * 128 * DH;
#pragma unroll
    for (int i = 0; i < 4; i++) {
      int f = i * 256 + tid;
      int kk = f >> 3, c8 = (f & 7) ^ (kk & 7);
      async16(ksrc + (size_t)kk * DH + c8 * 8, base + (size_t)f * 8);
    }
  };
  auto stageV = [&](int ktile, int buf) {
    short* base = Smem + buf * 16384 + 8192;
    const short* vsrc = Vb + (size_t)ktile * 128;
#pragma unroll
    for (int i = 0; i < 4; i++) {
      int f = i * 256 + tid;
      int d = f >> 4, c16 = (f & 15) ^ (d & 15);
      async16(vsrc + (size_t)d * SEQ + c16 * 8, base + (size_t)f * 8);
    }
  };

  s16x8 qf[4];
#pragma unroll
  for (int ks = 0; ks < 4; ks++)
    qf[ks] = *(const s16x8*)(Qb + (size_t)(q0 + wave * 32 + l31) * DH + ks * 16 + h * 8);

  f32x16 oacc[2];
  oacc[0] = (f32x16)0.f;
  oacc[1] = (f32x16)0.f;
  float m_own = -3.0e38f, l_own = 0.f, aprev = 0.f;
  s16x8 pf[8];  // P fragments of the PREVIOUS tile (consumed next iter)
  const float C = 0.18033688011112042f;  // (1/sqrt(64)) * log2(e)

  stageK(0, 0);

  for (int kt = 0; kt <= qt; kt++) {
    const int cur = kt & 1;
    __syncthreads();  // K[kt] + V[kt-1] resident; all prior LDS reads done
    if (kt < qt) stageK(kt + 1, cur ^ 1);
    stageV(kt, cur);  // consumed by PV in iter kt+1 (or post-loop peel)
    const short* Ks = Smem + cur * 16384;

    // ---- QK^T(kt) ----
    f32x16 sacc[4];
#pragma unroll
    for (int T = 0; T < 4; T++) sacc[T] = (f32x16)0.f;
    __builtin_amdgcn_s_setprio(1);
#pragma unroll
    for (int ks = 0; ks < 4; ks++) {
#pragma unroll
      for (int T = 0; T < 4; T++) {
        s16x8 kf = *(const s16x8*)(Ks + (T * 32 + l31) * 64 + (((2 * ks + h) ^ (l31 & 7)) * 8));
        sacc[T] = __builtin_amdgcn_mfma_f32_32x32x16_bf16(kf, qf[ks], sacc[T], 0, 0, 0);
      }
    }
    __builtin_amdgcn_s_setprio(0);

    // ---- deferred PV(kt-1): independent of this tile's softmax, overlaps it ----
    if (kt > 0) {
      const short* Vp = Smem + (cur ^ 1) * 16384 + 8192;
#pragma unroll
      for (int r2 = 0; r2 < 16; r2++) {
        oacc[0][r2] *= aprev;
        oacc[1][r2] *= aprev;
      }
      __builtin_amdgcn_s_setprio(1);
#pragma unroll
      for (int kc = 0; kc < 8; kc++) {
#pragma unroll
        for (int td = 0; td < 2; td++) {
          s16x8 vf = *(const s16x8*)(Vp + (td * 32 + l31) * 128 + (((2 * kc + h) ^ (l31 & 15)) * 8));
          oacc[td] = __builtin_amdgcn_mfma_f32_32x32x16_bf16(vf, pf[kc], oacc[td], 0, 0, 0);
        }
      }
      __builtin_amdgcn_s_setprio(0);
    }

    // ---- mask + online softmax(kt) ----
    if (kt == qt) {
      int limit = wave * 32 + l31 - 4 * h;
#pragma unroll
      for (int T = 0; T < 4; T++)
#pragma unroll
        for (int r2 = 0; r2 < 16; r2++) {
          int kkc = T * 32 + (r2 & 3) + 8 * (r2 >> 2);
          if (kkc > limit) sacc[T][r2] = -3.0e38f;
        }
    }

    float tm[4];
#pragma unroll
    for (int T = 0; T < 4; T++) {
      float a = fmaxf(fmaxf(sacc[T][0], sacc[T][1]), fmaxf(sacc[T][2], sacc[T][3]));
      float b = fmaxf(fmaxf(sacc[T][4], sacc[T][5]), fmaxf(sacc[T][6], sacc[T][7]));
      float cc = fmaxf(fmaxf(sacc[T][8], sacc[T][9]), fmaxf(sacc[T][10], sacc[T][11]));
      float d = fmaxf(fmaxf(sacc[T][12], sacc[T][13]), fmaxf(sacc[T][14], sacc[T][15]));
      tm[T] = fmaxf(fmaxf(a, b), fmaxf(cc, d));
    }
    float mx = fmaxf(fmaxf(tm[0], tm[1]), fmaxf(tm[2], tm[3]));
    mx = fmaxf(mx, __shfl_xor(mx, 32, 64));
    float mnew = fmaxf(m_own, mx);
    float mb = mnew * C;
    float alpha = exp2fast(m_own * C - mb);
    m_own = mnew;

    float ts[4];
#pragma unroll
    for (int T = 0; T < 4; T++) {
#pragma unroll
      for (int r2 = 0; r2 < 16; r2++) sacc[T][r2] = exp2fast(fmaf(sacc[T][r2], C, -mb));
      float a = (sacc[T][0] + sacc[T][1]) + (sacc[T][2] + sacc[T][3]);
      float b = (sacc[T][4] + sacc[T][5]) + (sacc[T][6] + sacc[T][7]);
      float cc = (sacc[T][8] + sacc[T][9]) + (sacc[T][10] + sacc[T][11]);
      float d = (sacc[T][12] + sacc[T][13]) + (sacc[T][14] + sacc[T][15]);
      ts[T] = (a + b) + (cc + d);
    }
    float rsum = (ts[0] + ts[1]) + (ts[2] + ts[3]);
    rsum += __shfl_xor(rsum, 32, 64);
    l_own = l_own * alpha + rsum;

    // ---- pack P(kt) -> pf for next iteration's PV (proven shfl_xor path) ----
#pragma unroll
    for (int T = 0; T < 4; T++) {
      unsigned P0 = pk2(sacc[T][0], sacc[T][1]);
      unsigned P1 = pk2(sacc[T][2], sacc[T][3]);
      unsigned P2 = pk2(sacc[T][4], sacc[T][5]);
      unsigned P3 = pk2(sacc[T][6], sacc[T][7]);
      unsigned P4 = pk2(sacc[T][8], sacc[T][9]);
      unsigned P5 = pk2(sacc[T][10], sacc[T][11]);
      unsigned P6 = pk2(sacc[T][12], sacc[T][13]);
      unsigned P7 = pk2(sacc[T][14], sacc[T][15]);
      unsigned R0 = (unsigned)__shfl_xor((int)(h ? P0 : P2), 32, 64);
      unsigned R1 = (unsigned)__shfl_xor((int)(h ? P1 : P3), 32, 64);
      unsigned R2 = (unsigned)__shfl_xor((int)(h ? P4 : P6), 32, 64);
      unsigned R3 = (unsigned)__shfl_xor((int)(h ? P5 : P7), 32, 64);
      u32x4 lo, hi;
      lo[0] = h ? R0 : P0; lo[1] = h ? R1 : P1; lo[2] = h ? P2 : R0; lo[3] = h ? P3 : R1;
      hi[0] = h ? R2 : P4; hi[1] = h ? R3 : P5; hi[2] = h ? P6 : R2; hi[3] = h ? P7 : R3;
      pf[2 * T] = __builtin_bit_cast(s16x8, lo);
      pf[2 * T + 1] = __builtin_bit_cast(s16x8, hi);
    }

    aprev = alpha;
  }

  // ---- peeled final PV(qt) ----
  __syncthreads();  // drains V[qt] stage; all waves past their last LDS reads
  {
    const short* Vp = Smem + (qt & 1) * 16384 + 8192;
#pragma unroll
    for (int r2 = 0; r2 < 16; r2++) {
      oacc[0][r2] *= aprev;
      oacc[1][r2] *= aprev;
    }
    __builtin_amdgcn_s_setprio(1);
#pragma unroll
    for (int kc = 0; kc < 8; kc++) {
#pragma unroll
      for (int td = 0; td < 2; td++) {
        s16x8 vf = *(const s16x8*)(Vp + (td * 32 + l31) * 128 + (((2 * kc + h) ^ (l31 & 15)) * 8));
        oacc[td] = __builtin_amdgcn_mfma_f32_32x32x16_bf16(vf, pf[kc], oacc[td], 0, 0, 0);
      }
    }
    __builtin_amdgcn_s_setprio(0);
  }
  __syncthreads();  // epilogue scratch below overlaps the V LDS regions

  const int b = bh >> 4, head = bh & 15;
  float inv = rcpfast(l_own);
  const int g = lane >> 3, d4 = (lane & 7) * 4;
#pragma unroll
  for (int td = 0; td < 2; td++) {
    float* tb = (float*)Smem + (size_t)(wave * 2 + td) * 1056;  // 32 d-rows x 33 (pad)
#pragma unroll
    for (int r2 = 0; r2 < 16; r2++) {
      int d_loc = (r2 & 3) + 8 * (r2 >> 2) + 4 * h;
      tb[d_loc * 33 + l31] = oacc[td][r2] * inv;
    }
#pragma unroll
    for (int j = 0; j < 4; j++) {
      int qq = j * 8 + g;
      float x0 = tb[(d4 + 0) * 33 + qq];
      float x1 = tb[(d4 + 1) * 33 + qq];
      float x2 = tb[(d4 + 2) * 33 + qq];
      float x3 = tb[(d4 + 3) * 33 + qq];
      uint2 pkd;
      pkd.x = (unsigned)f2bf(x0) | ((unsigned)f2bf(x1) << 16);
      pkd.y = (unsigned)f2bf(x2) | ((unsigned)f2bf(x3) << 16);
      int q = q0 + wave * 32 + qq;
      *(uint2*)(O + ((size_t)(b * SEQ + q)) * DM + head * DH + td * 32 + d4) = pkd;
    }
  }
}

// ---------------- host launch ----------------
extern "C" void kernel_launch(void* const* d_in, const int* in_sizes, int n_in,
                              void* d_out, int out_size, void* d_ws, size_t ws_size,
                              hipStream_t stream) {
  const float* x  = (const float*)d_in[0];
  const float* wq = (const float*)d_in[1];
  const float* wk = (const float*)d_in[2];
  const float* wv = (const float*)d_in[3];
  const float* wo = (const float*)d_in[4];

  short* ws = (short*)d_ws;
  short* Xb  = ws;
  short* Wqb = Xb + (size_t)NROWS * DM;     // 4 weights contiguous from here
  short* Wkb = Wqb + (size_t)DM * DM;
  short* Wvb = Wkb + (size_t)DM * DM;
  short* Wob = Wvb + (size_t)DM * DM;
  short* Qb  = Wob + (size_t)DM * DM;       // [B,NH,SEQ,DH]
  short* Kb  = Qb + (size_t)NROWS * DM;
  short* Vtb = Kb + (size_t)NROWS * DM;     // [B,NH,DH,SEQ]
  short* Ob  = Xb;                          // alias: X dead after QKV GEMMs

  // opt-in for 80KB dynamic LDS (host-side attribute, not a stream op ->
  // graph-capture safe; idempotent)
  static bool attr_done = false;
  if (!attr_done) {
    (void)hipFuncSetAttribute((const void*)gemm_qkv,
                              hipFuncAttributeMaxDynamicSharedMemorySize, 81920);
    attr_done = true;
  }

  int total_chunks = NROWS * DM / 8 + 4 * (DM * DM / 8);
  cast_all<<<total_chunks / 256, 256, 0, stream>>>(x, wq, wk, wv, wo, Xb, Wqb);

  gemm_qkv<<<dim3(8, 32), 512, 81920, stream>>>(Xb, Wqb, Wkb, Wvb, Qb, Kb, Vtb);

  attn_kernel<<<1024, 256, 0, stream>>>(Qb, Kb, Vtb, Ob);

  gemm_o<<<dim3(8, 32), 256, 0, stream>>>(Ob, Wob, (float*)d_out);
}

// Round 9
// 237.022 us; speedup vs baseline: 1.0721x; 1.0448x over previous
//
#include <hip/hip_runtime.h>
#include <stdint.h>
#include <stddef.h>

#define SEQ 2048
#define NH 16
#define DH 64
#define DM 1024
#define NROWS 8192  // B*T

typedef __attribute__((ext_vector_type(4))) float f32x4;
typedef __attribute__((ext_vector_type(16))) float f32x16;
typedef __attribute__((ext_vector_type(8))) short s16x8;
typedef __attribute__((ext_vector_type(4))) unsigned u32x4;

__device__ __forceinline__ unsigned short f2bf(float f) {
  unsigned int u = __builtin_bit_cast(unsigned int, f);
  u += 0x7fffu + ((u >> 16) & 1u);
  return (unsigned short)(u >> 16);
}

__device__ __forceinline__ float exp2fast(float x) {
#if __has_builtin(__builtin_amdgcn_exp2f)
  return __builtin_amdgcn_exp2f(x);
#else
  return exp2f(x);
#endif
}

__device__ __forceinline__ float rcpfast(float x) {
#if __has_builtin(__builtin_amdgcn_rcpf)
  return __builtin_amdgcn_rcpf(x);
#else
  return 1.0f / x;
#endif
}

// pack two f32 -> (bf16(lo) | bf16(hi)<<16), truncating (P in (0,1], rel err < 2^-8)
__device__ __forceinline__ unsigned pk2(float lo, float hi) {
  return __builtin_amdgcn_perm(__builtin_bit_cast(unsigned, hi),
                               __builtin_bit_cast(unsigned, lo), 0x07060302u);
}

// R2/R3: permlane32_swap(u,u) self-alias degenerates -> shfl_xor only.
// R7: occupancy ceiling != achieved; 512 blocks = no backfill queue -> keep
//     1024 small attn blocks + LPT.
// R8: setprio on lockstep-wave attn = null/negative (m190 regime, not m191's
//     independent-wave regime) -> removed. attn cross-round noise ~ +/-10%.

__device__ __forceinline__ void async16(const void* g, void* l) {
  __builtin_amdgcn_global_load_lds(
      (const __attribute__((address_space(1))) unsigned int*)g,
      (__attribute__((address_space(3))) unsigned int*)l, 16, 0, 0);
}

// ---------------- fused fp32 -> bf16 cast: x + 4 weights, one launch ----------------
__global__ __launch_bounds__(256) void cast_all(const float* __restrict__ x,
                                                const float* __restrict__ w0,
                                                const float* __restrict__ w1,
                                                const float* __restrict__ w2,
                                                const float* __restrict__ w3,
                                                short* __restrict__ Xb,
                                                short* __restrict__ Wb) {
  int g = blockIdx.x * 256 + threadIdx.x;  // chunk of 8 floats
  const float* src;
  short* dst;
  int off;
  if (g < NROWS * DM / 8) {
    src = x; dst = Xb; off = g;
  } else {
    int r = g - NROWS * DM / 8;
    int w = r >> 17;             // 0..3  (DM*DM/8 = 131072 chunks per weight)
    off = r & 131071;
    src = (w == 0) ? w0 : (w == 1) ? w1 : (w == 2) ? w2 : w3;
    dst = Wb + ((size_t)w << 20);
  }
  const float4* s4 = (const float4*)src;
  float4 a = s4[2 * off], b = s4[2 * off + 1];
  s16x8 o;
  o[0] = (short)f2bf(a.x); o[1] = (short)f2bf(a.y);
  o[2] = (short)f2bf(a.z); o[3] = (short)f2bf(a.w);
  o[4] = (short)f2bf(b.x); o[5] = (short)f2bf(b.y);
  o[6] = (short)f2bf(b.z); o[7] = (short)f2bf(b.w);
  *(s16x8*)(dst + (size_t)8 * off) = o;
}

// ---------------- FUSED QKV projection GEMM (R6 structure, kept) ----------------
// BM=256, BK=32, double-buffered 80KB dynamic LDS, grid (8,32) = 1 block/CU,
// bn-column pinned per XCD.
__global__ __launch_bounds__(512, 2) void gemm_qkv(const short* __restrict__ X,
                                                   const short* __restrict__ Wq,
                                                   const short* __restrict__ Wk,
                                                   const short* __restrict__ Wv,
                                                   short* __restrict__ Qo,
                                                   short* __restrict__ Ko,
                                                   short* __restrict__ Vo) {
  extern __shared__ __align__(16) short smem[];  // 2 x (X 8192 | W0 4096 | W1 4096 | W2 4096)
  const int tid = threadIdx.x;
  const int lane = tid & 63, wave = tid >> 6;
  const int l15 = lane & 15, quad = lane >> 4;
  const int bn = blockIdx.x * 128;
  const int bm = blockIdx.y * 256;
  const int wm = (wave >> 1) * 64, wn = (wave & 1) * 64;

  const short* Ab = X + (size_t)bm * DM;
  const short* W0 = Wq + (size_t)bn * DM;
  const short* W1 = Wk + (size_t)bn * DM;
  const short* W2 = Wv + (size_t)bn * DM;

  f32x4 acc[3][4][4];
#pragma unroll
  for (int g = 0; g < 3; g++)
#pragma unroll
    for (int i = 0; i < 4; i++)
#pragma unroll
      for (int j = 0; j < 4; j++) acc[g][i][j] = (f32x4)0.f;

  auto stage = [&](int k, int buf) {
    short* base = smem + buf * 20480;
    const int k0 = k * 32;
#pragma unroll
    for (int i = 0; i < 2; i++) {
      int f = i * 512 + tid;
      int row = f >> 2;
      int c = ((f & 3) ^ (row & 3) ^ ((row >> 2) & 1)) * 8;
      async16(Ab + (size_t)row * DM + k0 + c, base + (size_t)f * 8);
    }
    {
      int f = tid;
      int row = f >> 2;
      int c = ((f & 3) ^ (row & 3) ^ ((row >> 2) & 1)) * 8;
      size_t go = (size_t)row * DM + k0 + c;
      async16(W0 + go, base + 8192 + (size_t)f * 8);
      async16(W1 + go, base + 12288 + (size_t)f * 8);
      async16(W2 + go, base + 16384 + (size_t)f * 8);
    }
  };

  stage(0, 0);
  __syncthreads();

  const int sl = (l15 & 3) ^ ((l15 >> 2) & 1);
  for (int k = 0; k < 32; k++) {
    const int buf = k & 1;
    if (k < 31) stage(k + 1, buf ^ 1);  // prefetch rides under compute(k)
    const short* base = smem + buf * 20480;

    s16x8 af[4];
#pragma unroll
    for (int t = 0; t < 4; t++)
      af[t] = *(const s16x8*)(base + (size_t)(wm + t * 16 + l15) * 32 + (size_t)((quad ^ sl) * 8));
#pragma unroll
    for (int g = 0; g < 3; g++) {
      const short* wb = base + 8192 + g * 4096;
      s16x8 bfr[4];
#pragma unroll
      for (int t = 0; t < 4; t++)
        bfr[t] = *(const s16x8*)(wb + (size_t)(wn + t * 16 + l15) * 32 + (size_t)((quad ^ sl) * 8));
#pragma unroll
      for (int mt = 0; mt < 4; mt++)
#pragma unroll
        for (int nt = 0; nt < 4; nt++) {
          if (g == 2)  // V: swap operands so tokens land in lanes (coalesced V^T store)
            acc[2][mt][nt] = __builtin_amdgcn_mfma_f32_16x16x32_bf16(bfr[nt], af[mt], acc[2][mt][nt], 0, 0, 0);
          else
            acc[g][mt][nt] = __builtin_amdgcn_mfma_f32_16x16x32_bf16(af[mt], bfr[nt], acc[g][mt][nt], 0, 0, 0);
        }
    }
    __syncthreads();
  }

  // Q, K: [B,NH,SEQ,DH] scatter
#pragma unroll
  for (int g = 0; g < 2; g++) {
    short* Dst = g ? Ko : Qo;
#pragma unroll
    for (int mt = 0; mt < 4; mt++)
#pragma unroll
      for (int r = 0; r < 4; r++)
#pragma unroll
        for (int nt = 0; nt < 4; nt++) {
          int m = bm + wm + mt * 16 + quad * 4 + r;
          int n = bn + wn + nt * 16 + l15;
          int b = m >> 11, t = m & (SEQ - 1);
          int hh = n >> 6, d = n & 63;
          Dst[((((size_t)b * NH + hh) * SEQ + t) << 6) + d] = (short)f2bf(acc[g][mt][nt][r]);
        }
  }
  // V: [B,NH,DH,SEQ] (transposed D: col = token, row = d)
#pragma unroll
  for (int mt = 0; mt < 4; mt++)
#pragma unroll
    for (int r = 0; r < 4; r++)
#pragma unroll
      for (int nt = 0; nt < 4; nt++) {
        int n = bn + wn + nt * 16 + quad * 4 + r;  // d-dim
        int m = bm + wm + mt * 16 + l15;           // token
        int b = m >> 11, t = m & (SEQ - 1);
        int hh = n >> 6, d = n & 63;
        Vo[(((size_t)b * NH + hh) * DH + d) * SEQ + t] = (short)f2bf(acc[2][mt][nt][r]);
      }
}

// ---------------- output projection GEMM (R9: gemm_qkv-style pipeline) ----------------
// Old structure: 16 k-chunks, barrier BETWEEN stage and compute -> vmcnt(0)
// drain exposed staging latency 16x at 4 waves/block. New: exact structural
// mirror of the verified gemm_qkv: BM=256/BN=128/BK=32, 512 threads (8 waves,
// 64x64/wave), double-buffered 48KB static LDS, stage(k+1) issued before
// compute(k), ONE barrier per iter. Same swizzle relations as gemm_qkv
// (numerically verified there). Grid (8,32) = 256 blocks = 1/CU; bn-column
// pinned per XCD -> W_O slice L2-resident. fp32 C out, k ascending (same
// accumulation order as before -> absmax unchanged).
__global__ __launch_bounds__(512, 2) void gemm_o(const short* __restrict__ A,
                                                 const short* __restrict__ B,
                                                 float* __restrict__ C) {
  __shared__ __align__(16) short smem[2 * 12288];  // per buf: A 8192 | B 4096 shorts
  const int tid = threadIdx.x;
  const int lane = tid & 63, wave = tid >> 6;
  const int l15 = lane & 15, quad = lane >> 4;
  const int bm = blockIdx.y * 256, bn = blockIdx.x * 128;
  const int wm = (wave >> 1) * 64, wn = (wave & 1) * 64;

  const short* Ab = A + (size_t)bm * DM;
  const short* Bb = B + (size_t)bn * DM;

  f32x4 acc[4][4];
#pragma unroll
  for (int i = 0; i < 4; i++)
#pragma unroll
    for (int j = 0; j < 4; j++) acc[i][j] = (f32x4)0.f;

  auto stage = [&](int k, int buf) {
    short* base = smem + buf * 12288;
    const int k0 = k * 32;
    // A: 256 rows x 4 chunks = 1024; 512 threads -> 2 each
#pragma unroll
    for (int i = 0; i < 2; i++) {
      int f = i * 512 + tid;
      int row = f >> 2;
      int c = ((f & 3) ^ (row & 3) ^ ((row >> 2) & 1)) * 8;
      async16(Ab + (size_t)row * DM + k0 + c, base + (size_t)f * 8);
    }
    // B: 128 rows x 4 chunks = 512; 1 each
    {
      int f = tid;
      int row = f >> 2;
      int c = ((f & 3) ^ (row & 3) ^ ((row >> 2) & 1)) * 8;
      async16(Bb + (size_t)row * DM + k0 + c, base + 8192 + (size_t)f * 8);
    }
  };

  stage(0, 0);
  __syncthreads();

  const int sl = (l15 & 3) ^ ((l15 >> 2) & 1);
  for (int k = 0; k < 32; k++) {
    const int buf = k & 1;
    if (k < 31) stage(k + 1, buf ^ 1);  // prefetch rides under compute(k)
    const short* base = smem + buf * 12288;

    s16x8 af[4], bfr[4];
#pragma unroll
    for (int t = 0; t < 4; t++)
      af[t] = *(const s16x8*)(base + (size_t)(wm + t * 16 + l15) * 32 + (size_t)((quad ^ sl) * 8));
#pragma unroll
    for (int t = 0; t < 4; t++)
      bfr[t] = *(const s16x8*)(base + 8192 + (size_t)(wn + t * 16 + l15) * 32 + (size_t)((quad ^ sl) * 8));
#pragma unroll
    for (int mt = 0; mt < 4; mt++)
#pragma unroll
      for (int nt = 0; nt < 4; nt++)
        acc[mt][nt] = __builtin_amdgcn_mfma_f32_16x16x32_bf16(af[mt], bfr[nt], acc[mt][nt], 0, 0, 0);
    __syncthreads();
  }

#pragma unroll
  for (int mt = 0; mt < 4; mt++)
#pragma unroll
    for (int r = 0; r < 4; r++) {
      int m = bm + wm + mt * 16 + quad * 4 + r;
#pragma unroll
      for (int nt = 0; nt < 4; nt++)
        C[(size_t)m * DM + bn + wn + nt * 16 + l15] = acc[mt][nt][r];
    }
}

// ---------------- causal flash attention (R6 proven kernel, byte-identical) ----------------
// QBLK=128, 256 threads, 64KB LDS, one barrier/iter, deferred PV, LPT dispatch
// (qt = 15 - blockIdx>>6), XCD-pinned bh octets. Best measured: 72.7us (R6).
__global__ __launch_bounds__(256, 2) void attn_kernel(const short* __restrict__ Q,
                                                      const short* __restrict__ K,
                                                      const short* __restrict__ V,
                                                      short* __restrict__ O) {
  __shared__ __align__(16) short Smem[2 * 16384];  // buf b: K at b*16384, V at +8192

  const int tid = threadIdx.x;
  const int lane = tid & 63, wave = tid >> 6;
  const int l31 = lane & 31, h = lane >> 5;

  const int r = blockIdx.x & 63;
  const int qt = 15 - (blockIdx.x >> 6);     // LPT: longest blocks dispatch first
  const int bh = (r & 7) * 8 + (r >> 3);     // XCD (blockIdx%8) -> bh octet
  const int q0 = qt * 128;

  const short* Qb = Q + (size_t)bh * SEQ * DH;
  const short* Kb = K + (size_t)bh * SEQ * DH;
  const short* Vb = V + (size_t)bh * DH * SEQ;

  auto stageK = [&](int ktile, int buf) {
    short* base = Smem + buf * 16384;
    const short* ksrc = Kb + (size_t)ktile * 128 * DH;
#pragma unroll
    for (int i = 0; i < 4; i++) {
      int f = i * 256 + tid;
      int kk = f >> 3, c8 = (f & 7) ^ (kk & 7);
      async16(ksrc + (size_t)kk * DH + c8 * 8, base + (size_t)f * 8);
    }
  };
  auto stageV = [&](int ktile, int buf) {
    short* base = Smem + buf * 16384 + 8192;
    const short* vsrc = Vb + (size_t)ktile * 128;
#pragma unroll
    for (int i = 0; i < 4; i++) {
      int f = i * 256 + tid;
      int d = f >> 4, c16 = (f & 15) ^ (d & 15);
      async16(vsrc + (size_t)d * SEQ + c16 * 8, base + (size_t)f * 8);
    }
  };

  s16x8 qf[4];
#pragma unroll
  for (int ks = 0; ks < 4; ks++)
    qf[ks] = *(const s16x8*)(Qb + (size_t)(q0 + wave * 32 + l31) * DH + ks * 16 + h * 8);

  f32x16 oacc[2];
  oacc[0] = (f32x16)0.f;
  oacc[1] = (f32x16)0.f;
  float m_own = -3.0e38f, l_own = 0.f, aprev = 0.f;
  s16x8 pf[8];  // P fragments of the PREVIOUS tile (consumed next iter)
  const float C = 0.18033688011112042f;  // (1/sqrt(64)) * log2(e)

  stageK(0, 0);

  for (int kt = 0; kt <= qt; kt++) {
    const int cur = kt & 1;
    __syncthreads();  // K[kt] + V[kt-1] resident; all prior LDS reads done
    if (kt < qt) stageK(kt + 1, cur ^ 1);
    stageV(kt, cur);  // consumed by PV in iter kt+1 (or post-loop peel)
    const short* Ks = Smem + cur * 16384;

    // ---- QK^T(kt) ----
    f32x16 sacc[4];
#pragma unroll
    for (int T = 0; T < 4; T++) sacc[T] = (f32x16)0.f;
#pragma unroll
    for (int ks = 0; ks < 4; ks++) {
#pragma unroll
      for (int T = 0; T < 4; T++) {
        s16x8 kf = *(const s16x8*)(Ks + (T * 32 + l31) * 64 + (((2 * ks + h) ^ (l31 & 7)) * 8));
        sacc[T] = __builtin_amdgcn_mfma_f32_32x32x16_bf16(kf, qf[ks], sacc[T], 0, 0, 0);
      }
    }

    // ---- deferred PV(kt-1): independent of this tile's softmax, overlaps it ----
    if (kt > 0) {
      const short* Vp = Smem + (cur ^ 1) * 16384 + 8192;
#pragma unroll
      for (int r2 = 0; r2 < 16; r2++) {
        oacc[0][r2] *= aprev;
        oacc[1][r2] *= aprev;
      }
#pragma unroll
      for (int kc = 0; kc < 8; kc++) {
#pragma unroll
        for (int td = 0; td < 2; td++) {
          s16x8 vf = *(const s16x8*)(Vp + (td * 32 + l31) * 128 + (((2 * kc + h) ^ (l31 & 15)) * 8));
          oacc[td] = __builtin_amdgcn_mfma_f32_32x32x16_bf16(vf, pf[kc], oacc[td], 0, 0, 0);
        }
      }
    }

    // ---- mask + online softmax(kt) ----
    if (kt == qt) {
      int limit = wave * 32 + l31 - 4 * h;
#pragma unroll
      for (int T = 0; T < 4; T++)
#pragma unroll
        for (int r2 = 0; r2 < 16; r2++) {
          int kkc = T * 32 + (r2 & 3) + 8 * (r2 >> 2);
          if (kkc > limit) sacc[T][r2] = -3.0e38f;
        }
    }

    float tm[4];
#pragma unroll
    for (int T = 0; T < 4; T++) {
      float a = fmaxf(fmaxf(sacc[T][0], sacc[T][1]), fmaxf(sacc[T][2], sacc[T][3]));
      float b = fmaxf(fmaxf(sacc[T][4], sacc[T][5]), fmaxf(sacc[T][6], sacc[T][7]));
      float cc = fmaxf(fmaxf(sacc[T][8], sacc[T][9]), fmaxf(sacc[T][10], sacc[T][11]));
      float d = fmaxf(fmaxf(sacc[T][12], sacc[T][13]), fmaxf(sacc[T][14], sacc[T][15]));
      tm[T] = fmaxf(fmaxf(a, b), fmaxf(cc, d));
    }
    float mx = fmaxf(fmaxf(tm[0], tm[1]), fmaxf(tm[2], tm[3]));
    mx = fmaxf(mx, __shfl_xor(mx, 32, 64));
    float mnew = fmaxf(m_own, mx);
    float mb = mnew * C;
    float alpha = exp2fast(m_own * C - mb);
    m_own = mnew;

    float ts[4];
#pragma unroll
    for (int T = 0; T < 4; T++) {
#pragma unroll
      for (int r2 = 0; r2 < 16; r2++) sacc[T][r2] = exp2fast(fmaf(sacc[T][r2], C, -mb));
      float a = (sacc[T][0] + sacc[T][1]) + (sacc[T][2] + sacc[T][3]);
      float b = (sacc[T][4] + sacc[T][5]) + (sacc[T][6] + sacc[T][7]);
      float cc = (sacc[T][8] + sacc[T][9]) + (sacc[T][10] + sacc[T][11]);
      float d = (sacc[T][12] + sacc[T][13]) + (sacc[T][14] + sacc[T][15]);
      ts[T] = (a + b) + (cc + d);
    }
    float rsum = (ts[0] + ts[1]) + (ts[2] + ts[3]);
    rsum += __shfl_xor(rsum, 32, 64);
    l_own = l_own * alpha + rsum;

    // ---- pack P(kt) -> pf for next iteration's PV (proven shfl_xor path) ----
#pragma unroll
    for (int T = 0; T < 4; T++) {
      unsigned P0 = pk2(sacc[T][0], sacc[T][1]);
      unsigned P1 = pk2(sacc[T][2], sacc[T][3]);
      unsigned P2 = pk2(sacc[T][4], sacc[T][5]);
      unsigned P3 = pk2(sacc[T][6], sacc[T][7]);
      unsigned P4 = pk2(sacc[T][8], sacc[T][9]);
      unsigned P5 = pk2(sacc[T][10], sacc[T][11]);
      unsigned P6 = pk2(sacc[T][12], sacc[T][13]);
      unsigned P7 = pk2(sacc[T][14], sacc[T][15]);
      unsigned R0 = (unsigned)__shfl_xor((int)(h ? P0 : P2), 32, 64);
      unsigned R1 = (unsigned)__shfl_xor((int)(h ? P1 : P3), 32, 64);
      unsigned R2 = (unsigned)__shfl_xor((int)(h ? P4 : P6), 32, 64);
      unsigned R3 = (unsigned)__shfl_xor((int)(h ? P5 : P7), 32, 64);
      u32x4 lo, hi;
      lo[0] = h ? R0 : P0; lo[1] = h ? R1 : P1; lo[2] = h ? P2 : R0; lo[3] = h ? P3 : R1;
      hi[0] = h ? R2 : P4; hi[1] = h ? R3 : P5; hi[2] = h ? P6 : R2; hi[3] = h ? P7 : R3;
      pf[2 * T] = __builtin_bit_cast(s16x8, lo);
      pf[2 * T + 1] = __builtin_bit_cast(s16x8, hi);
    }

    aprev = alpha;
  }

  // ---- peeled final PV(qt) ----
  __syncthreads();  // drains V[qt] stage; all waves past their last LDS reads
  {
    const short* Vp = Smem + (qt & 1) * 16384 + 8192;
#pragma unroll
    for (int r2 = 0; r2 < 16; r2++) {
      oacc[0][r2] *= aprev;
      oacc[1][r2] *= aprev;
    }
#pragma unroll
    for (int kc = 0; kc < 8; kc++) {
#pragma unroll
      for (int td = 0; td < 2; td++) {
        s16x8 vf = *(const s16x8*)(Vp + (td * 32 + l31) * 128 + (((2 * kc + h) ^ (l31 & 15)) * 8));
        oacc[td] = __builtin_amdgcn_mfma_f32_32x32x16_bf16(vf, pf[kc], oacc[td], 0, 0, 0);
      }
    }
  }
  __syncthreads();  // epilogue scratch below overlaps the V LDS regions

  const int b = bh >> 4, head = bh & 15;
  float inv = rcpfast(l_own);
  const int g = lane >> 3, d4 = (lane & 7) * 4;
#pragma unroll
  for (int td = 0; td < 2; td++) {
    float* tb = (float*)Smem + (size_t)(wave * 2 + td) * 1056;  // 32 d-rows x 33 (pad)
#pragma unroll
    for (int r2 = 0; r2 < 16; r2++) {
      int d_loc = (r2 & 3) + 8 * (r2 >> 2) + 4 * h;
      tb[d_loc * 33 + l31] = oacc[td][r2] * inv;
    }
#pragma unroll
    for (int j = 0; j < 4; j++) {
      int qq = j * 8 + g;
      float x0 = tb[(d4 + 0) * 33 + qq];
      float x1 = tb[(d4 + 1) * 33 + qq];
      float x2 = tb[(d4 + 2) * 33 + qq];
      float x3 = tb[(d4 + 3) * 33 + qq];
      uint2 pkd;
      pkd.x = (unsigned)f2bf(x0) | ((unsigned)f2bf(x1) << 16);
      pkd.y = (unsigned)f2bf(x2) | ((unsigned)f2bf(x3) << 16);
      int q = q0 + wave * 32 + qq;
      *(uint2*)(O + ((size_t)(b * SEQ + q)) * DM + head * DH + td * 32 + d4) = pkd;
    }
  }
}

// ---------------- host launch ----------------
extern "C" void kernel_launch(void* const* d_in, const int* in_sizes, int n_in,
                              void* d_out, int out_size, void* d_ws, size_t ws_size,
                              hipStream_t stream) {
  const float* x  = (const float*)d_in[0];
  const float* wq = (const float*)d_in[1];
  const float* wk = (const float*)d_in[2];
  const float* wv = (const float*)d_in[3];
  const float* wo = (const float*)d_in[4];

  short* ws = (short*)d_ws;
  short* Xb  = ws;
  short* Wqb = Xb + (size_t)NROWS * DM;     // 4 weights contiguous from here
  short* Wkb = Wqb + (size_t)DM * DM;
  short* Wvb = Wkb + (size_t)DM * DM;
  short* Wob = Wvb + (size_t)DM * DM;
  short* Qb  = Wob + (size_t)DM * DM;       // [B,NH,SEQ,DH]
  short* Kb  = Qb + (size_t)NROWS * DM;
  short* Vtb = Kb + (size_t)NROWS * DM;     // [B,NH,DH,SEQ]
  short* Ob  = Xb;                          // alias: X dead after QKV GEMMs

  // opt-in for 80KB dynamic LDS (host-side attribute, not a stream op ->
  // graph-capture safe; idempotent)
  static bool attr_done = false;
  if (!attr_done) {
    (void)hipFuncSetAttribute((const void*)gemm_qkv,
                              hipFuncAttributeMaxDynamicSharedMemorySize, 81920);
    attr_done = true;
  }

  int total_chunks = NROWS * DM / 8 + 4 * (DM * DM / 8);
  cast_all<<<total_chunks / 256, 256, 0, stream>>>(x, wq, wk, wv, wo, Xb, Wqb);

  gemm_qkv<<<dim3(8, 32), 512, 81920, stream>>>(Xb, Wqb, Wkb, Wvb, Qb, Kb, Vtb);

  attn_kernel<<<1024, 256, 0, stream>>>(Qb, Kb, Vtb, Ob);

  gemm_o<<<dim3(8, 32), 512, 0, stream>>>(Ob, Wob, (float*)d_out);
}

// Round 11
// 228.888 us; speedup vs baseline: 1.1102x; 1.0355x over previous
//
#include <hip/hip_runtime.h>
#include <stdint.h>
#include <stddef.h>

#define SEQ 2048
#define NH 16
#define DH 64
#define DM 1024
#define NROWS 8192  // B*T

typedef __attribute__((ext_vector_type(4))) float f32x4;
typedef __attribute__((ext_vector_type(16))) float f32x16;
typedef __attribute__((ext_vector_type(8))) short s16x8;
typedef __attribute__((ext_vector_type(4))) unsigned u32x4;
typedef __attribute__((ext_vector_type(2))) unsigned u32x2;

__device__ __forceinline__ unsigned short f2bf(float f) {
  unsigned int u = __builtin_bit_cast(unsigned int, f);
  u += 0x7fffu + ((u >> 16) & 1u);
  return (unsigned short)(u >> 16);
}

__device__ __forceinline__ float exp2fast(float x) {
#if __has_builtin(__builtin_amdgcn_exp2f)
  return __builtin_amdgcn_exp2f(x);
#else
  return exp2f(x);
#endif
}

__device__ __forceinline__ float rcpfast(float x) {
#if __has_builtin(__builtin_amdgcn_rcpf)
  return __builtin_amdgcn_rcpf(x);
#else
  return 1.0f / x;
#endif
}

// pack two f32 -> (bf16(lo) | bf16(hi)<<16), truncating (P in (0,1], rel err < 2^-8)
__device__ __forceinline__ unsigned pk2(float lo, float hi) {
  return __builtin_amdgcn_perm(__builtin_bit_cast(unsigned, hi),
                               __builtin_bit_cast(unsigned, lo), 0x07060302u);
}

// R2/R3 refined: permlane32_swap(u,u) SELF-ALIAS (same value both operands)
// lets regalloc assign vdst==vsrc -> degenerate in-place swap -> broken
// REDUCTIONS (that was the 2.359 absmax in both R2+R3). With DISTINCT
// operands (the P-pack) both outputs map to the two input registers --
// exactly the instruction's in-place semantics -- and the R2-derived mapping
// lo={A_lo,B_lo}/hi={A_hi,B_hi} matches the shfl version word-for-word.
// Reductions stay on shfl_xor forever; pack uses permlane (T12, m214v22).
// R7: occupancy ceiling != achieved; 1024 small attn blocks + LPT, no merge.
// R8: setprio on lockstep-wave attn = null/negative (m190 regime) -> removed.
// R10: infra failure (container), kernel never ran -> resubmitted unchanged.

__device__ __forceinline__ void async16(const void* g, void* l) {
  __builtin_amdgcn_global_load_lds(
      (const __attribute__((address_space(1))) unsigned int*)g,
      (__attribute__((address_space(3))) unsigned int*)l, 16, 0, 0);
}

// ---------------- fused fp32 -> bf16 cast: x + 4 weights, one launch ----------------
__global__ __launch_bounds__(256) void cast_all(const float* __restrict__ x,
                                                const float* __restrict__ w0,
                                                const float* __restrict__ w1,
                                                const float* __restrict__ w2,
                                                const float* __restrict__ w3,
                                                short* __restrict__ Xb,
                                                short* __restrict__ Wb) {
  int g = blockIdx.x * 256 + threadIdx.x;  // chunk of 8 floats
  const float* src;
  short* dst;
  int off;
  if (g < NROWS * DM / 8) {
    src = x; dst = Xb; off = g;
  } else {
    int r = g - NROWS * DM / 8;
    int w = r >> 17;             // 0..3  (DM*DM/8 = 131072 chunks per weight)
    off = r & 131071;
    src = (w == 0) ? w0 : (w == 1) ? w1 : (w == 2) ? w2 : w3;
    dst = Wb + ((size_t)w << 20);
  }
  const float4* s4 = (const float4*)src;
  float4 a = s4[2 * off], b = s4[2 * off + 1];
  s16x8 o;
  o[0] = (short)f2bf(a.x); o[1] = (short)f2bf(a.y);
  o[2] = (short)f2bf(a.z); o[3] = (short)f2bf(a.w);
  o[4] = (short)f2bf(b.x); o[5] = (short)f2bf(b.y);
  o[6] = (short)f2bf(b.z); o[7] = (short)f2bf(b.w);
  *(s16x8*)(dst + (size_t)8 * off) = o;
}

// ---------------- FUSED QKV projection GEMM (R6 structure, kept) ----------------
// BM=256, BK=32, double-buffered 80KB dynamic LDS, grid (8,32) = 1 block/CU,
// bn-column pinned per XCD.
__global__ __launch_bounds__(512, 2) void gemm_qkv(const short* __restrict__ X,
                                                   const short* __restrict__ Wq,
                                                   const short* __restrict__ Wk,
                                                   const short* __restrict__ Wv,
                                                   short* __restrict__ Qo,
                                                   short* __restrict__ Ko,
                                                   short* __restrict__ Vo) {
  extern __shared__ __align__(16) short smem[];  // 2 x (X 8192 | W0 4096 | W1 4096 | W2 4096)
  const int tid = threadIdx.x;
  const int lane = tid & 63, wave = tid >> 6;
  const int l15 = lane & 15, quad = lane >> 4;
  const int bn = blockIdx.x * 128;
  const int bm = blockIdx.y * 256;
  const int wm = (wave >> 1) * 64, wn = (wave & 1) * 64;

  const short* Ab = X + (size_t)bm * DM;
  const short* W0 = Wq + (size_t)bn * DM;
  const short* W1 = Wk + (size_t)bn * DM;
  const short* W2 = Wv + (size_t)bn * DM;

  f32x4 acc[3][4][4];
#pragma unroll
  for (int g = 0; g < 3; g++)
#pragma unroll
    for (int i = 0; i < 4; i++)
#pragma unroll
      for (int j = 0; j < 4; j++) acc[g][i][j] = (f32x4)0.f;

  auto stage = [&](int k, int buf) {
    short* base = smem + buf * 20480;
    const int k0 = k * 32;
#pragma unroll
    for (int i = 0; i < 2; i++) {
      int f = i * 512 + tid;
      int row = f >> 2;
      int c = ((f & 3) ^ (row & 3) ^ ((row >> 2) & 1)) * 8;
      async16(Ab + (size_t)row * DM + k0 + c, base + (size_t)f * 8);
    }
    {
      int f = tid;
      int row = f >> 2;
      int c = ((f & 3) ^ (row & 3) ^ ((row >> 2) & 1)) * 8;
      size_t go = (size_t)row * DM + k0 + c;
      async16(W0 + go, base + 8192 + (size_t)f * 8);
      async16(W1 + go, base + 12288 + (size_t)f * 8);
      async16(W2 + go, base + 16384 + (size_t)f * 8);
    }
  };

  stage(0, 0);
  __syncthreads();

  const int sl = (l15 & 3) ^ ((l15 >> 2) & 1);
  for (int k = 0; k < 32; k++) {
    const int buf = k & 1;
    if (k < 31) stage(k + 1, buf ^ 1);  // prefetch rides under compute(k)
    const short* base = smem + buf * 20480;

    s16x8 af[4];
#pragma unroll
    for (int t = 0; t < 4; t++)
      af[t] = *(const s16x8*)(base + (size_t)(wm + t * 16 + l15) * 32 + (size_t)((quad ^ sl) * 8));
#pragma unroll
    for (int g = 0; g < 3; g++) {
      const short* wb = base + 8192 + g * 4096;
      s16x8 bfr[4];
#pragma unroll
      for (int t = 0; t < 4; t++)
        bfr[t] = *(const s16x8*)(wb + (size_t)(wn + t * 16 + l15) * 32 + (size_t)((quad ^ sl) * 8));
#pragma unroll
      for (int mt = 0; mt < 4; mt++)
#pragma unroll
        for (int nt = 0; nt < 4; nt++) {
          if (g == 2)  // V: swap operands so tokens land in lanes (coalesced V^T store)
            acc[2][mt][nt] = __builtin_amdgcn_mfma_f32_16x16x32_bf16(bfr[nt], af[mt], acc[2][mt][nt], 0, 0, 0);
          else
            acc[g][mt][nt] = __builtin_amdgcn_mfma_f32_16x16x32_bf16(af[mt], bfr[nt], acc[g][mt][nt], 0, 0, 0);
        }
    }
    __syncthreads();
  }

  // Q, K: [B,NH,SEQ,DH] scatter
#pragma unroll
  for (int g = 0; g < 2; g++) {
    short* Dst = g ? Ko : Qo;
#pragma unroll
    for (int mt = 0; mt < 4; mt++)
#pragma unroll
      for (int r = 0; r < 4; r++)
#pragma unroll
        for (int nt = 0; nt < 4; nt++) {
          int m = bm + wm + mt * 16 + quad * 4 + r;
          int n = bn + wn + nt * 16 + l15;
          int b = m >> 11, t = m & (SEQ - 1);
          int hh = n >> 6, d = n & 63;
          Dst[((((size_t)b * NH + hh) * SEQ + t) << 6) + d] = (short)f2bf(acc[g][mt][nt][r]);
        }
  }
  // V: [B,NH,DH,SEQ] (transposed D: col = token, row = d)
#pragma unroll
  for (int mt = 0; mt < 4; mt++)
#pragma unroll
    for (int r = 0; r < 4; r++)
#pragma unroll
      for (int nt = 0; nt < 4; nt++) {
        int n = bn + wn + nt * 16 + quad * 4 + r;  // d-dim
        int m = bm + wm + mt * 16 + l15;           // token
        int b = m >> 11, t = m & (SEQ - 1);
        int hh = n >> 6, d = n & 63;
        Vo[(((size_t)b * NH + hh) * DH + d) * SEQ + t] = (short)f2bf(acc[2][mt][nt][r]);
      }
}

// ---------------- output projection GEMM (R9 pipeline, kept: 247.6->237.0) ----------------
// BM=256/BN=128/BK=32, 512 threads, double-buffered 48KB LDS, stage(k+1)
// before compute(k), one barrier/iter. Grid (8,32) = 1/CU, bn per XCD.
__global__ __launch_bounds__(512, 2) void gemm_o(const short* __restrict__ A,
                                                 const short* __restrict__ B,
                                                 float* __restrict__ C) {
  __shared__ __align__(16) short smem[2 * 12288];  // per buf: A 8192 | B 4096 shorts
  const int tid = threadIdx.x;
  const int lane = tid & 63, wave = tid >> 6;
  const int l15 = lane & 15, quad = lane >> 4;
  const int bm = blockIdx.y * 256, bn = blockIdx.x * 128;
  const int wm = (wave >> 1) * 64, wn = (wave & 1) * 64;

  const short* Ab = A + (size_t)bm * DM;
  const short* Bb = B + (size_t)bn * DM;

  f32x4 acc[4][4];
#pragma unroll
  for (int i = 0; i < 4; i++)
#pragma unroll
    for (int j = 0; j < 4; j++) acc[i][j] = (f32x4)0.f;

  auto stage = [&](int k, int buf) {
    short* base = smem + buf * 12288;
    const int k0 = k * 32;
#pragma unroll
    for (int i = 0; i < 2; i++) {
      int f = i * 512 + tid;
      int row = f >> 2;
      int c = ((f & 3) ^ (row & 3) ^ ((row >> 2) & 1)) * 8;
      async16(Ab + (size_t)row * DM + k0 + c, base + (size_t)f * 8);
    }
    {
      int f = tid;
      int row = f >> 2;
      int c = ((f & 3) ^ (row & 3) ^ ((row >> 2) & 1)) * 8;
      async16(Bb + (size_t)row * DM + k0 + c, base + 8192 + (size_t)f * 8);
    }
  };

  stage(0, 0);
  __syncthreads();

  const int sl = (l15 & 3) ^ ((l15 >> 2) & 1);
  for (int k = 0; k < 32; k++) {
    const int buf = k & 1;
    if (k < 31) stage(k + 1, buf ^ 1);  // prefetch rides under compute(k)
    const short* base = smem + buf * 12288;

    s16x8 af[4], bfr[4];
#pragma unroll
    for (int t = 0; t < 4; t++)
      af[t] = *(const s16x8*)(base + (size_t)(wm + t * 16 + l15) * 32 + (size_t)((quad ^ sl) * 8));
#pragma unroll
    for (int t = 0; t < 4; t++)
      bfr[t] = *(const s16x8*)(base + 8192 + (size_t)(wn + t * 16 + l15) * 32 + (size_t)((quad ^ sl) * 8));
#pragma unroll
    for (int mt = 0; mt < 4; mt++)
#pragma unroll
      for (int nt = 0; nt < 4; nt++)
        acc[mt][nt] = __builtin_amdgcn_mfma_f32_16x16x32_bf16(af[mt], bfr[nt], acc[mt][nt], 0, 0, 0);
    __syncthreads();
  }

#pragma unroll
  for (int mt = 0; mt < 4; mt++)
#pragma unroll
    for (int r = 0; r < 4; r++) {
      int m = bm + wm + mt * 16 + quad * 4 + r;
#pragma unroll
      for (int nt = 0; nt < 4; nt++)
        C[(size_t)m * DM + bn + wn + nt * 16 + l15] = acc[mt][nt][r];
    }
}

// ---------------- causal flash attention (R10 = R6 structure + permlane pack) ----------------
// QBLK=128, 256 threads, 64KB LDS, one barrier/iter, deferred PV, LPT dispatch,
// XCD-pinned bh. R10: P-pack via permlane32_swap with DISTINCT operands
// (T12; replaces 16 ds_bpermute + ~48 cndmask with 8 VALU swaps per iter).
// Reductions remain shfl_xor (self-alias hazard, R2/R3).
__global__ __launch_bounds__(256, 2) void attn_kernel(const short* __restrict__ Q,
                                                      const short* __restrict__ K,
                                                      const short* __restrict__ V,
                                                      short* __restrict__ O) {
  __shared__ __align__(16) short Smem[2 * 16384];  // buf b: K at b*16384, V at +8192

  const int tid = threadIdx.x;
  const int lane = tid & 63, wave = tid >> 6;
  const int l31 = lane & 31, h = lane >> 5;

  const int r = blockIdx.x & 63;
  const int qt = 15 - (blockIdx.x >> 6);     // LPT: longest blocks dispatch first
  const int bh = (r & 7) * 8 + (r >> 3);     // XCD (blockIdx%8) -> bh octet
  const int q0 = qt * 128;

  const short* Qb = Q + (size_t)bh * SEQ * DH;
  const short* Kb = K + (size_t)bh * SEQ * DH;
  const short* Vb = V + (size_t)bh * DH * SEQ;

  auto stageK = [&](int ktile, int buf) {
    short* base = Smem + buf * 16384;
    const short* ksrc = Kb + (size_t)ktile * 128 * DH;
#pragma unroll
    for (int i = 0; i < 4; i++) {
      int f = i * 256 + tid;
      int kk = f >> 3, c8 = (f & 7) ^ (kk & 7);
      async16(ksrc + (size_t)kk * DH + c8 * 8, base + (size_t)f * 8);
    }
  };
  auto stageV = [&](int ktile, int buf) {
    short* base = Smem + buf * 16384 + 8192;
    const short* vsrc = Vb + (size_t)ktile * 128;
#pragma unroll
    for (int i = 0; i < 4; i++) {
      int f = i * 256 + tid;
      int d = f >> 4, c16 = (f & 15) ^ (d & 15);
      async16(vsrc + (size_t)d * SEQ + c16 * 8, base + (size_t)f * 8);
    }
  };

  s16x8 qf[4];
#pragma unroll
  for (int ks = 0; ks < 4; ks++)
    qf[ks] = *(const s16x8*)(Qb + (size_t)(q0 + wave * 32 + l31) * DH + ks * 16 + h * 8);

  f32x16 oacc[2];
  oacc[0] = (f32x16)0.f;
  oacc[1] = (f32x16)0.f;
  float m_own = -3.0e38f, l_own = 0.f, aprev = 0.f;
  s16x8 pf[8];  // P fragments of the PREVIOUS tile (consumed next iter)
  const float C = 0.18033688011112042f;  // (1/sqrt(64)) * log2(e)

  stageK(0, 0);

  for (int kt = 0; kt <= qt; kt++) {
    const int cur = kt & 1;
    __syncthreads();  // K[kt] + V[kt-1] resident; all prior LDS reads done
    if (kt < qt) stageK(kt + 1, cur ^ 1);
    stageV(kt, cur);  // consumed by PV in iter kt+1 (or post-loop peel)
    const short* Ks = Smem + cur * 16384;

    // ---- QK^T(kt) ----
    f32x16 sacc[4];
#pragma unroll
    for (int T = 0; T < 4; T++) sacc[T] = (f32x16)0.f;
#pragma unroll
    for (int ks = 0; ks < 4; ks++) {
#pragma unroll
      for (int T = 0; T < 4; T++) {
        s16x8 kf = *(const s16x8*)(Ks + (T * 32 + l31) * 64 + (((2 * ks + h) ^ (l31 & 7)) * 8));
        sacc[T] = __builtin_amdgcn_mfma_f32_32x32x16_bf16(kf, qf[ks], sacc[T], 0, 0, 0);
      }
    }

    // ---- deferred PV(kt-1): independent of this tile's softmax, overlaps it ----
    if (kt > 0) {
      const short* Vp = Smem + (cur ^ 1) * 16384 + 8192;
#pragma unroll
      for (int r2 = 0; r2 < 16; r2++) {
        oacc[0][r2] *= aprev;
        oacc[1][r2] *= aprev;
      }
#pragma unroll
      for (int kc = 0; kc < 8; kc++) {
#pragma unroll
        for (int td = 0; td < 2; td++) {
          s16x8 vf = *(const s16x8*)(Vp + (td * 32 + l31) * 128 + (((2 * kc + h) ^ (l31 & 15)) * 8));
          oacc[td] = __builtin_amdgcn_mfma_f32_32x32x16_bf16(vf, pf[kc], oacc[td], 0, 0, 0);
        }
      }
    }

    // ---- mask + online softmax(kt) ----
    if (kt == qt) {
      int limit = wave * 32 + l31 - 4 * h;
#pragma unroll
      for (int T = 0; T < 4; T++)
#pragma unroll
        for (int r2 = 0; r2 < 16; r2++) {
          int kkc = T * 32 + (r2 & 3) + 8 * (r2 >> 2);
          if (kkc > limit) sacc[T][r2] = -3.0e38f;
        }
    }

    float tm[4];
#pragma unroll
    for (int T = 0; T < 4; T++) {
      float a = fmaxf(fmaxf(sacc[T][0], sacc[T][1]), fmaxf(sacc[T][2], sacc[T][3]));
      float b = fmaxf(fmaxf(sacc[T][4], sacc[T][5]), fmaxf(sacc[T][6], sacc[T][7]));
      float cc = fmaxf(fmaxf(sacc[T][8], sacc[T][9]), fmaxf(sacc[T][10], sacc[T][11]));
      float d = fmaxf(fmaxf(sacc[T][12], sacc[T][13]), fmaxf(sacc[T][14], sacc[T][15]));
      tm[T] = fmaxf(fmaxf(a, b), fmaxf(cc, d));
    }
    float mx = fmaxf(fmaxf(tm[0], tm[1]), fmaxf(tm[2], tm[3]));
    mx = fmaxf(mx, __shfl_xor(mx, 32, 64));
    float mnew = fmaxf(m_own, mx);
    float mb = mnew * C;
    float alpha = exp2fast(m_own * C - mb);
    m_own = mnew;

    float ts[4];
#pragma unroll
    for (int T = 0; T < 4; T++) {
#pragma unroll
      for (int r2 = 0; r2 < 16; r2++) sacc[T][r2] = exp2fast(fmaf(sacc[T][r2], C, -mb));
      float a = (sacc[T][0] + sacc[T][1]) + (sacc[T][2] + sacc[T][3]);
      float b = (sacc[T][4] + sacc[T][5]) + (sacc[T][6] + sacc[T][7]);
      float cc = (sacc[T][8] + sacc[T][9]) + (sacc[T][10] + sacc[T][11]);
      float d = (sacc[T][12] + sacc[T][13]) + (sacc[T][14] + sacc[T][15]);
      ts[T] = (a + b) + (cc + d);
    }
    float rsum = (ts[0] + ts[1]) + (ts[2] + ts[3]);
    rsum += __shfl_xor(rsum, 32, 64);
    l_own = l_own * alpha + rsum;

    // ---- pack P(kt) -> pf for next iteration's PV ----
    // permlane32_swap with DISTINCT operands: s02[0]={P0_lo,P2_lo} = lo[0],
    // s02[1]={P0_hi,P2_hi} = lo[2] -- word-for-word equal to the shfl mapping.
#pragma unroll
    for (int T = 0; T < 4; T++) {
      unsigned P0 = pk2(sacc[T][0], sacc[T][1]);
      unsigned P1 = pk2(sacc[T][2], sacc[T][3]);
      unsigned P2 = pk2(sacc[T][4], sacc[T][5]);
      unsigned P3 = pk2(sacc[T][6], sacc[T][7]);
      unsigned P4 = pk2(sacc[T][8], sacc[T][9]);
      unsigned P5 = pk2(sacc[T][10], sacc[T][11]);
      unsigned P6 = pk2(sacc[T][12], sacc[T][13]);
      unsigned P7 = pk2(sacc[T][14], sacc[T][15]);
      u32x4 lo, hi;
#if __has_builtin(__builtin_amdgcn_permlane32_swap)
      u32x2 s02 = __builtin_amdgcn_permlane32_swap(P0, P2, false, false);
      u32x2 s13 = __builtin_amdgcn_permlane32_swap(P1, P3, false, false);
      u32x2 s46 = __builtin_amdgcn_permlane32_swap(P4, P6, false, false);
      u32x2 s57 = __builtin_amdgcn_permlane32_swap(P5, P7, false, false);
      lo[0] = s02[0]; lo[1] = s13[0]; lo[2] = s02[1]; lo[3] = s13[1];
      hi[0] = s46[0]; hi[1] = s57[0]; hi[2] = s46[1]; hi[3] = s57[1];
#else
      unsigned R0 = (unsigned)__shfl_xor((int)(h ? P0 : P2), 32, 64);
      unsigned R1 = (unsigned)__shfl_xor((int)(h ? P1 : P3), 32, 64);
      unsigned R2 = (unsigned)__shfl_xor((int)(h ? P4 : P6), 32, 64);
      unsigned R3 = (unsigned)__shfl_xor((int)(h ? P5 : P7), 32, 64);
      lo[0] = h ? R0 : P0; lo[1] = h ? R1 : P1; lo[2] = h ? P2 : R0; lo[3] = h ? P3 : R1;
      hi[0] = h ? R2 : P4; hi[1] = h ? R3 : P5; hi[2] = h ? P6 : R2; hi[3] = h ? P7 : R3;
#endif
      pf[2 * T] = __builtin_bit_cast(s16x8, lo);
      pf[2 * T + 1] = __builtin_bit_cast(s16x8, hi);
    }

    aprev = alpha;
  }

  // ---- peeled final PV(qt) ----
  __syncthreads();  // drains V[qt] stage; all waves past their last LDS reads
  {
    const short* Vp = Smem + (qt & 1) * 16384 + 8192;
#pragma unroll
    for (int r2 = 0; r2 < 16; r2++) {
      oacc[0][r2] *= aprev;
      oacc[1][r2] *= aprev;
    }
#pragma unroll
    for (int kc = 0; kc < 8; kc++) {
#pragma unroll
      for (int td = 0; td < 2; td++) {
        s16x8 vf = *(const s16x8*)(Vp + (td * 32 + l31) * 128 + (((2 * kc + h) ^ (l31 & 15)) * 8));
        oacc[td] = __builtin_amdgcn_mfma_f32_32x32x16_bf16(vf, pf[kc], oacc[td], 0, 0, 0);
      }
    }
  }
  __syncthreads();  // epilogue scratch below overlaps the V LDS regions

  const int b = bh >> 4, head = bh & 15;
  float inv = rcpfast(l_own);
  const int g = lane >> 3, d4 = (lane & 7) * 4;
#pragma unroll
  for (int td = 0; td < 2; td++) {
    float* tb = (float*)Smem + (size_t)(wave * 2 + td) * 1056;  // 32 d-rows x 33 (pad)
#pragma unroll
    for (int r2 = 0; r2 < 16; r2++) {
      int d_loc = (r2 & 3) + 8 * (r2 >> 2) + 4 * h;
      tb[d_loc * 33 + l31] = oacc[td][r2] * inv;
    }
#pragma unroll
    for (int j = 0; j < 4; j++) {
      int qq = j * 8 + g;
      float x0 = tb[(d4 + 0) * 33 + qq];
      float x1 = tb[(d4 + 1) * 33 + qq];
      float x2 = tb[(d4 + 2) * 33 + qq];
      float x3 = tb[(d4 + 3) * 33 + qq];
      uint2 pkd;
      pkd.x = (unsigned)f2bf(x0) | ((unsigned)f2bf(x1) << 16);
      pkd.y = (unsigned)f2bf(x2) | ((unsigned)f2bf(x3) << 16);
      int q = q0 + wave * 32 + qq;
      *(uint2*)(O + ((size_t)(b * SEQ + q)) * DM + head * DH + td * 32 + d4) = pkd;
    }
  }
}

// ---------------- host launch ----------------
extern "C" void kernel_launch(void* const* d_in, const int* in_sizes, int n_in,
                              void* d_out, int out_size, void* d_ws, size_t ws_size,
                              hipStream_t stream) {
  const float* x  = (const float*)d_in[0];
  const float* wq = (const float*)d_in[1];
  const float* wk = (const float*)d_in[2];
  const float* wv = (const float*)d_in[3];
  const float* wo = (const float*)d_in[4];

  short* ws = (short*)d_ws;
  short* Xb  = ws;
  short* Wqb = Xb + (size_t)NROWS * DM;     // 4 weights contiguous from here
  short* Wkb = Wqb + (size_t)DM * DM;
  short* Wvb = Wkb + (size_t)DM * DM;
  short* Wob = Wvb + (size_t)DM * DM;
  short* Qb  = Wob + (size_t)DM * DM;       // [B,NH,SEQ,DH]
  short* Kb  = Qb + (size_t)NROWS * DM;
  short* Vtb = Kb + (size_t)NROWS * DM;     // [B,NH,DH,SEQ]
  short* Ob  = Xb;                          // alias: X dead after QKV GEMMs

  // opt-in for 80KB dynamic LDS (host-side attribute, not a stream op ->
  // graph-capture safe; idempotent)
  static bool attr_done = false;
  if (!attr_done) {
    (void)hipFuncSetAttribute((const void*)gemm_qkv,
                              hipFuncAttributeMaxDynamicSharedMemorySize, 81920);
    attr_done = true;
  }

  int total_chunks = NROWS * DM / 8 + 4 * (DM * DM / 8);
  cast_all<<<total_chunks / 256, 256, 0, stream>>>(x, wq, wk, wv, wo, Xb, Wqb);

  gemm_qkv<<<dim3(8, 32), 512, 81920, stream>>>(Xb, Wqb, Wkb, Wvb, Qb, Kb, Vtb);

  attn_kernel<<<1024, 256, 0, stream>>>(Qb, Kb, Vtb, Ob);

  gemm_o<<<dim3(8, 32), 512, 0, stream>>>(Ob, Wob, (float*)d_out);
}